// Round 6
// baseline (843.604 us; speedup 1.0000x reference)
//
#include <hip/hip_runtime.h>

#define DEV __device__ __forceinline__

typedef float  f32x4  __attribute__((ext_vector_type(4)));
typedef __bf16 bf16x4 __attribute__((ext_vector_type(4)));
typedef __bf16 bf16x8 __attribute__((ext_vector_type(8)));

DEV unsigned short f2bf(float f) {
  unsigned u = __float_as_uint(f);
  u += 0x7fffu + ((u >> 16) & 1u);           // round-to-nearest-even
  return (unsigned short)(u >> 16);
}

DEV void cp16(const void* g, void* l) {      // async global->LDS, 16B/lane
  __builtin_amdgcn_global_load_lds((const __attribute__((address_space(1))) void*)g,
                                   (__attribute__((address_space(3))) void*)l, 16, 0, 0);
}

// ---------------- prep: weights fp32->bf16 + qkv bias assembly --------------
__global__ __launch_bounds__(256) void prep_kernel(
    const float* __restrict__ qkv_w, const float* __restrict__ proj_w,
    const float* __restrict__ q_bias, const float* __restrict__ v_bias,
    unsigned short* __restrict__ wq, unsigned short* __restrict__ wp,
    float* __restrict__ qkvb)
{
  int gid = blockIdx.x * 256 + threadIdx.x;     // 1024 blocks -> 262144 = 196608+65536
  if (gid < 196608) wq[gid] = f2bf(qkv_w[gid]);
  else              wp[gid - 196608] = f2bf(proj_w[gid - 196608]);
  if (gid < 768)
    qkvb[gid] = (gid < 256) ? q_bias[gid] : ((gid < 512) ? 0.f : v_bias[gid - 512]);
}

// -------- X fp32 -> bf16 (plain row-major) + 16 zero pad rows ---------------
__global__ __launch_bounds__(256) void xbf16(
    const float* __restrict__ X, unsigned short* __restrict__ Xb)
{
  size_t gid = (size_t)blockIdx.x * 256 + threadIdx.x;   // 12546 blocks
  if (gid < 3211264) {
    const float4* xp = (const float4*)X;
    float4 f0 = xp[2 * gid], f1 = xp[2 * gid + 1];
    bf16x8 u;
    u[0] = (__bf16)f0.x; u[1] = (__bf16)f0.y; u[2] = (__bf16)f0.z; u[3] = (__bf16)f0.w;
    u[4] = (__bf16)f1.x; u[5] = (__bf16)f1.y; u[6] = (__bf16)f1.z; u[7] = (__bf16)f1.w;
    ((bf16x8*)Xb)[gid] = u;
  } else {
    bf16x8 z = {};
    ((bf16x8*)Xb)[gid] = z;                   // zero-pad rows 100352..100367
  }
}

// ---------------- CPB MLP: table16[r][h] = 16*sigmoid(mlp(tab[r])) ----------
__global__ __launch_bounds__(64) void cpb_mlp(
    const float* __restrict__ tab, const float* __restrict__ w1,
    const float* __restrict__ b1, const float* __restrict__ w2,
    float* __restrict__ table16)
{
  int r = blockIdx.x;            // 169 rows
  int t = threadIdx.x;           // 64 lanes
  float x0 = tab[r * 2 + 0], x1 = tab[r * 2 + 1];
  float part[8];
#pragma unroll
  for (int h = 0; h < 8; ++h) part[h] = 0.f;
  for (int j = t; j < 512; j += 64) {
    float hv = fmaxf(w1[j * 2 + 0] * x0 + w1[j * 2 + 1] * x1 + b1[j], 0.f);
#pragma unroll
    for (int h = 0; h < 8; ++h) part[h] += hv * w2[h * 512 + j];
  }
#pragma unroll
  for (int h = 0; h < 8; ++h) {
    float v = part[h];
    for (int off = 32; off > 0; off >>= 1) v += __shfl_down(v, off, 64);
    if (t == 0) table16[r * 8 + h] = 16.f / (1.f + expf(-v));
  }
}

// -------- bias64[h][i][j] (8x64x64, -1e30 pad) and mask64 (0-pad), *log2(e)
__global__ __launch_bounds__(256) void bmb(
    const float* __restrict__ t16, const int* __restrict__ ridx,
    const float* __restrict__ mask, float* __restrict__ bias64,
    float* __restrict__ mask64)
{
  const float L2E = 1.44269504f;
  int gid = blockIdx.x * 256 + threadIdx.x;   // 1152 blocks = 294912 = 32768 + 262144
  int p = gid & 4095, i = p >> 6, j = p & 63;
  bool valid = (i < 49) && (j < 49);
  if (gid < 32768) {
    int h = gid >> 12;
    // -1e30 padding folds the attention mask for i>=49 / j>=49 rows/cols
    bias64[gid] = valid ? t16[ridx[i * 49 + j] * 8 + h] * L2E : -1e30f;
  } else {
    int g2 = gid - 32768;
    int w = g2 >> 12;
    mask64[g2] = valid ? mask[w * 2401 + i * 49 + j] * L2E : 0.f;
  }
}

// ============ FUSED QKV GEMM + window attention (occupancy build) ===========
// block = 1 window, 4 independent waves (no __syncthreads); wave w -> heads
// {2w,2w+1}. X and W fragments read directly from global (L1/L2-hot).
// LDS = 4 x 8 KB per-wave region only: [0,4K) K-bounce -> vT; [4K,8K)
// Q-bounce; [0,8K) P. __launch_bounds__(256,4) pins VGPR<=128 -> 16 waves/CU.
__global__ __launch_bounds__(256, 4) void qkv_attn(
    const unsigned short* __restrict__ Xb, const unsigned short* __restrict__ W,
    const float* __restrict__ qkvb, const float* __restrict__ logit_scale,
    const float* __restrict__ bias64, const float* __restrict__ mask64,
    unsigned short* __restrict__ aout)
{
  __shared__ __align__(1024) char smem[32768];
  const int t = threadIdx.x, w = t >> 6, l = t & 63, quad = l >> 4, l15 = l & 15;
  char* myr = smem + w * 8192;            // per-wave region
  const int win = blockIdx.x;             // 2048 windows
  const int wtok = win * 49;
  const unsigned short* xrow = Xb + (size_t)wtok * 256;
  const int bslot = (quad ^ ((l15 >> 1) & 3)) * 16;   // bounce bank swizzle

  // GEMM: M=64 tokens (global X), N=32 head dims (global W), K=256.
  // acc[nt][mA]: lane l15 -> token mA*16+l15 ; quad*4+r -> d = nt*16+quad*4+r.
  auto do_gemm = [&](int wrb, f32x4 (&acc)[2][4]) {
#pragma unroll
    for (int kt = 0; kt < 4; ++kt)
#pragma unroll
      for (int kk = 0; kk < 2; ++kk) {
        const int co = kt * 64 + (4 * kk + quad) * 8;
        bf16x8 wf[2], xf[4];
#pragma unroll
        for (int nt = 0; nt < 2; ++nt)
          wf[nt] = *(const bf16x8*)(W + (size_t)(wrb + nt * 16 + l15) * 256 + co);
#pragma unroll
        for (int mA = 0; mA < 4; ++mA)
          xf[mA] = *(const bf16x8*)(xrow + (size_t)(mA * 16 + l15) * 256 + co);
#pragma unroll
        for (int nt = 0; nt < 2; ++nt)
#pragma unroll
          for (int mA = 0; mA < 4; ++mA)
            acc[nt][mA] = __builtin_amdgcn_mfma_f32_16x16x32_bf16(wf[nt], xf[mA], acc[nt][mA], 0, 0, 0);
      }
  };

  // pack acc(+bias) -> bounce LDS (no wait). 16B at (tok row)*64 + bslot holds
  // k-elems d = {q*4+0..3, 16+q*4+0..3} -- the d' fragment permutation.
  auto pack_write = [&](f32x4 (&acc)[2][4], const float* bias, char* dst) {
    const f32x4 b0 = *(const f32x4*)(bias + quad * 4);
    const f32x4 b1 = *(const f32x4*)(bias + 16 + quad * 4);
#pragma unroll
    for (int mA = 0; mA < 4; ++mA) {
      bf16x8 u;
      u[0] = (__bf16)(acc[0][mA][0] + b0[0]); u[1] = (__bf16)(acc[0][mA][1] + b0[1]);
      u[2] = (__bf16)(acc[0][mA][2] + b0[2]); u[3] = (__bf16)(acc[0][mA][3] + b0[3]);
      u[4] = (__bf16)(acc[1][mA][0] + b1[0]); u[5] = (__bf16)(acc[1][mA][1] + b1[1]);
      u[6] = (__bf16)(acc[1][mA][2] + b1[2]); u[7] = (__bf16)(acc[1][mA][3] + b1[3]);
      *(bf16x8*)(dst + (mA * 16 + l15) * 64 + bslot) = u;
    }
  };

#pragma unroll 1
  for (int hh = 0; hh < 2; ++hh) {
    const int h = 2 * w + hh;

    // ---- K GEMM -> bounce[0,4K);  Q GEMM (hides K write) -> bounce[4K,8K)
    f32x4 ka[2][4] = {};
    do_gemm(256 + h * 32, ka);
    pack_write(ka, qkvb + 256 + h * 32, myr);
    f32x4 qa[2][4] = {};
    do_gemm(h * 32, qa);
    pack_write(qa, qkvb + h * 32, myr + 4096);
    asm volatile("s_waitcnt lgkmcnt(0)" ::: "memory");
    __builtin_amdgcn_sched_barrier(0);
    bf16x8 kf[4], qf[4];
#pragma unroll
    for (int mt = 0; mt < 4; ++mt)
      kf[mt] = *(const bf16x8*)(myr + (mt * 16 + l15) * 64 + bslot);
#pragma unroll
    for (int nt = 0; nt < 4; ++nt)
      qf[nt] = *(const bf16x8*)(myr + 4096 + (nt * 16 + l15) * 64 + bslot);

    // ---- norms (perm-invariant); log2(e) folded into rqv ----
    const float scale = __expf(fminf(logit_scale[h], 4.60517019f)) * 1.44269504f;
    float rqv[4];
#pragma unroll
    for (int nt = 0; nt < 4; ++nt) {
      float s = 0.f;
#pragma unroll
      for (int d = 0; d < 8; ++d) { float f = (float)qf[nt][d]; s += f * f; }
      s += __shfl_xor(s, 16, 64); s += __shfl_xor(s, 32, 64);
      rqv[nt] = scale / fmaxf(sqrtf(s), 1e-12f);
    }
    float rkl[4];
#pragma unroll
    for (int mt = 0; mt < 4; ++mt) {
      float s = 0.f;
#pragma unroll
      for (int d = 0; d < 8; ++d) { float f = (float)kf[mt][d]; s += f * f; }
      s += __shfl_xor(s, 16, 64); s += __shfl_xor(s, 32, 64);
      rkl[mt] = 1.f / fmaxf(sqrtf(s), 1e-12f);
    }
    f32x4 rk4v[4];
#pragma unroll
    for (int mt = 0; mt < 4; ++mt)
#pragma unroll
      for (int r = 0; r < 4; ++r)
        rk4v[mt][r] = __shfl(rkl[mt], (quad << 2) + r, 16);

    // ---- V GEMM -> vT scatter into [0,4K) (kf already in regs) ----
    {
      f32x4 va[2][4] = {};
      do_gemm(512 + h * 32, va);
      const f32x4 vb0 = *(const f32x4*)(qkvb + 512 + h * 32 + quad * 4);
      const f32x4 vb1 = *(const f32x4*)(qkvb + 512 + h * 32 + 16 + quad * 4);
#pragma unroll
      for (int mA = 0; mA < 4; ++mA) {
        const int tok = mA * 16 + l15;
#pragma unroll
        for (int nt = 0; nt < 2; ++nt) {
#pragma unroll
          for (int r = 0; r < 4; ++r) {
            const int d = nt * 16 + quad * 4 + r;
            *(__bf16*)(myr + d * 128 + (((tok >> 3) ^ (d & 7)) << 4) + (tok & 7) * 2) =
                (__bf16)(va[nt][mA][r] + (nt ? vb1[r] : vb0[r]));
          }
        }
      }
    }

    // ---- S^T[j][i] = K . Q^T (register-only; overlaps vT ds_writes) ----
    f32x4 sacc[4][4] = {};
    __builtin_amdgcn_s_setprio(1);
#pragma unroll
    for (int mt = 0; mt < 4; ++mt)
#pragma unroll
      for (int nt = 0; nt < 4; ++nt)
        sacc[mt][nt] = __builtin_amdgcn_mfma_f32_16x16x32_bf16(kf[mt], qf[nt], sacc[mt][nt], 0, 0, 0);
    __builtin_amdgcn_s_setprio(0);

    asm volatile("s_waitcnt lgkmcnt(0)" ::: "memory");
    __builtin_amdgcn_sched_barrier(0);
    bf16x8 vf[2][2];
#pragma unroll
    for (int kk = 0; kk < 2; ++kk)
#pragma unroll
      for (int mt = 0; mt < 2; ++mt)
        vf[kk][mt] = *(const bf16x8*)(myr + (mt * 16 + l15) * 128
                                          + (((4 * kk + quad) ^ (l15 & 7)) * 16));
    asm volatile("s_waitcnt lgkmcnt(0)" ::: "memory");   // vf read before P clobbers
    __builtin_amdgcn_sched_barrier(0);

    // ---- softmax (log2 domain), P -> [0,8K) ----
    unsigned short* P = (unsigned short*)myr;
    const float* bh = bias64 + (size_t)h * 4096;
    const float* mw = mask64 + (size_t)(win & 63) * 4096;
    float rs4[4];
#pragma unroll
    for (int nt = 0; nt < 4; ++nt) {
      const int i = nt * 16 + l15;
      const float rqi = rqv[nt];
      float mx = -3e38f;
#pragma unroll
      for (int mt = 0; mt < 4; ++mt) {
        const int jb = mt * 16 + quad * 4;
        const f32x4 b4 = *(const f32x4*)(bh + i * 64 + jb);
        const f32x4 m4 = *(const f32x4*)(mw + i * 64 + jb);
#pragma unroll
        for (int r = 0; r < 4; ++r) {
          float sv = fmaf(sacc[mt][nt][r], rqi * rk4v[mt][r], b4[r] + m4[r]);
          sacc[mt][nt][r] = sv;
          mx = fmaxf(mx, sv);
        }
      }
      mx = fmaxf(mx, __shfl_xor(mx, 16, 64));
      mx = fmaxf(mx, __shfl_xor(mx, 32, 64));
      float sum = 0.f;
#pragma unroll
      for (int mt = 0; mt < 4; ++mt) {
        float pv[4];
#pragma unroll
        for (int r = 0; r < 4; ++r) {
          pv[r] = __builtin_amdgcn_exp2f(sacc[mt][nt][r] - mx);
          sum += pv[r];
        }
        bf16x4 pk;
        pk[0] = (__bf16)pv[0]; pk[1] = (__bf16)pv[1];
        pk[2] = (__bf16)pv[2]; pk[3] = (__bf16)pv[3];
        const int c = 2 * mt + (quad >> 1);
        *(bf16x4*)((char*)P + i * 128 + ((c ^ (i & 7)) * 16) + (quad & 1) * 8) = pk;
      }
      sum += __shfl_xor(sum, 16, 64);
      sum += __shfl_xor(sum, 32, 64);
      rs4[nt] = 1.f / sum;                  // normalization deferred to O store
    }
    asm volatile("s_waitcnt lgkmcnt(0)" ::: "memory");
    __builtin_amdgcn_sched_barrier(0);

    // ---- O^T[d][i] = V^T . P^T ----
    f32x4 oacc[2][4] = {};
#pragma unroll
    for (int kk = 0; kk < 2; ++kk) {
      bf16x8 pf[4];
#pragma unroll
      for (int nt = 0; nt < 4; ++nt)
        pf[nt] = *(const bf16x8*)((char*)P + (nt * 16 + l15) * 128
                                           + (((4 * kk + quad) ^ (l15 & 7)) * 16));
      __builtin_amdgcn_s_setprio(1);
#pragma unroll
      for (int mt = 0; mt < 2; ++mt)
#pragma unroll
        for (int nt = 0; nt < 4; ++nt)
          oacc[mt][nt] = __builtin_amdgcn_mfma_f32_16x16x32_bf16(vf[kk][mt], pf[nt], oacc[mt][nt], 0, 0, 0);
      __builtin_amdgcn_s_setprio(0);
    }

    // ---- store O (tok = nt*16+l15, d = mt*16+quad*4+r), rs applied here
#pragma unroll
    for (int nt = 0; nt < 4; ++nt) {
      const int tok = nt * 16 + l15;
      if (tok < 49) {
        unsigned short* op = aout + (size_t)(wtok + tok) * 256 + h * 32;
        const float rs = rs4[nt];
#pragma unroll
        for (int mt = 0; mt < 2; ++mt) {
          bf16x4 ov;
          ov[0] = (__bf16)(oacc[mt][nt][0] * rs); ov[1] = (__bf16)(oacc[mt][nt][1] * rs);
          ov[2] = (__bf16)(oacc[mt][nt][2] * rs); ov[3] = (__bf16)(oacc[mt][nt][3] * rs);
          *(bf16x4*)(op + mt * 16 + quad * 4) = ov;
        }
      }
    }
  }
}

// ---------------- proj GEMM: bf16 A/W, fp32 out, packed f32x4 stores --------
__global__ __launch_bounds__(256) void gemm_proj(
    const unsigned short* __restrict__ A, const unsigned short* __restrict__ W,
    const float* __restrict__ bias, float* __restrict__ Y)
{
  __shared__ __align__(1024) unsigned short sA[128 * 64];
  __shared__ __align__(1024) unsigned short sB[128 * 64];
  const int t = threadIdx.x, w = t >> 6, l = t & 63, quad = l >> 4, l15 = l & 15;
  const int bm = blockIdx.y * 128, bn = blockIdx.x * 128;
  const int wm = (w >> 1) * 64, wn = (w & 1) * 64;
  const int srow = t >> 3, sch = t & 7;
  const int sc = sch ^ (srow & 7);

  f32x4 acc[4][4] = {};                      // acc[nW][mA]
  for (int kt = 0; kt < 4; ++kt) {
    const int k0 = kt << 6;
    if (kt) __syncthreads();
#pragma unroll
    for (int i = 0; i < 4; ++i) {
      const int row = i * 32 + srow;
      cp16(A + (size_t)(bm + row) * 256 + k0 + sc * 8, sA + (i * 256 + w * 64) * 8);
      cp16(W + (size_t)(bn + row) * 256 + k0 + sc * 8, sB + (i * 256 + w * 64) * 8);
    }
    __syncthreads();
#pragma unroll
    for (int kk = 0; kk < 2; ++kk) {
      bf16x8 xf[4], wf[4];
#pragma unroll
      for (int mt = 0; mt < 4; ++mt)
        xf[mt] = *(const bf16x8*)&sA[(wm + mt * 16 + l15) * 64 + (((4 * kk + quad) ^ (l15 & 7)) * 8)];
#pragma unroll
      for (int nt = 0; nt < 4; ++nt)
        wf[nt] = *(const bf16x8*)&sB[(wn + nt * 16 + l15) * 64 + (((4 * kk + quad) ^ (l15 & 7)) * 8)];
#pragma unroll
      for (int nt = 0; nt < 4; ++nt)
#pragma unroll
        for (int mt = 0; mt < 4; ++mt)
          acc[nt][mt] = __builtin_amdgcn_mfma_f32_16x16x32_bf16(wf[nt], xf[mt], acc[nt][mt], 0, 0, 0);
    }
  }
  // epilogue: lane holds 4 consecutive cols -> f32x4 16B stores
#pragma unroll
  for (int mA = 0; mA < 4; ++mA) {
    const int row = bm + wm + mA * 16 + l15;
    float* orow = Y + (size_t)row * 256;
#pragma unroll
    for (int nW = 0; nW < 4; ++nW) {
      const int c0 = bn + wn + nW * 16 + quad * 4;
      const f32x4 bv = *(const f32x4*)(bias + c0);
      f32x4 v = acc[nW][mA];
      v[0] += bv[0]; v[1] += bv[1]; v[2] += bv[2]; v[3] += bv[3];
      *(f32x4*)(orow + c0) = v;
    }
  }
}

// ---------------------------------------------------------------------------
extern "C" void kernel_launch(void* const* d_in, const int* in_sizes, int n_in,
                              void* d_out, int out_size, void* d_ws, size_t ws_size,
                              hipStream_t stream) {
  const float* x           = (const float*)d_in[0];
  const float* mask        = (const float*)d_in[1];
  const float* qkv_w       = (const float*)d_in[2];
  const float* q_bias      = (const float*)d_in[3];
  const float* v_bias      = (const float*)d_in[4];
  const float* logit_scale = (const float*)d_in[5];
  const float* cpb_w1      = (const float*)d_in[6];
  const float* cpb_b1      = (const float*)d_in[7];
  const float* cpb_w2      = (const float*)d_in[8];
  const float* proj_w      = (const float*)d_in[9];
  const float* proj_b      = (const float*)d_in[10];
  const float* rel_tab     = (const float*)d_in[11];
  const int*   rel_idx     = (const int*)d_in[12];
  float*       out         = (float*)d_out;

  char* ws = (char*)d_ws;
  unsigned short* xbf     = (unsigned short*)(ws + 0);          // 51388416 (bf16 X + 16 pad rows)
  unsigned short* aows    = (unsigned short*)(ws + 154140672);  // 51380224
  unsigned short* wq      = (unsigned short*)(ws + 205520896);  // 393216
  unsigned short* wp      = (unsigned short*)(ws + 205914112);  // 131072
  float*          qkvb    = (float*)(ws + 206045184);           // 3072
  float*          table16 = (float*)(ws + 206048256);           // 5632
  float*          bias64  = (float*)(ws + 206053888);           // 131072
  float*          mask64  = (float*)(ws + 206184960);           // 1048576
  // end: 207233536

  prep_kernel<<<1024, 256, 0, stream>>>(qkv_w, proj_w, q_bias, v_bias, wq, wp, qkvb);
  cpb_mlp<<<169, 64, 0, stream>>>(rel_tab, cpb_w1, cpb_b1, cpb_w2, table16);
  bmb<<<1152, 256, 0, stream>>>(table16, rel_idx, mask, bias64, mask64);
  xbf16<<<12546, 256, 0, stream>>>(x, xbf);
  qkv_attn<<<2048, 256, 0, stream>>>(xbf, wq, qkvb, logit_scale, bias64, mask64, aows);
  gemm_proj<<<dim3(2, 784), 256, 0, stream>>>(aows, wp, proj_b, out);
}

// Round 7
// 456.831 us; speedup vs baseline: 1.8466x; 1.8466x over previous
//
#include <hip/hip_runtime.h>

#define DEV __device__ __forceinline__

typedef float  f32x4  __attribute__((ext_vector_type(4)));
typedef __bf16 bf16x4 __attribute__((ext_vector_type(4)));
typedef __bf16 bf16x8 __attribute__((ext_vector_type(8)));

DEV unsigned short f2bf(float f) {
  unsigned u = __float_as_uint(f);
  u += 0x7fffu + ((u >> 16) & 1u);           // round-to-nearest-even
  return (unsigned short)(u >> 16);
}

DEV void cp16(const void* g, void* l) {      // async global->LDS, 16B/lane
  __builtin_amdgcn_global_load_lds((const __attribute__((address_space(1))) void*)g,
                                   (__attribute__((address_space(3))) void*)l, 16, 0, 0);
}

// ---------------- prep: weights fp32->bf16 + qkv bias assembly --------------
__global__ __launch_bounds__(256) void prep_kernel(
    const float* __restrict__ qkv_w, const float* __restrict__ proj_w,
    const float* __restrict__ q_bias, const float* __restrict__ v_bias,
    unsigned short* __restrict__ wq, unsigned short* __restrict__ wp,
    float* __restrict__ qkvb)
{
  int gid = blockIdx.x * 256 + threadIdx.x;     // 1024 blocks -> 262144 = 196608+65536
  if (gid < 196608) wq[gid] = f2bf(qkv_w[gid]);
  else              wp[gid - 196608] = f2bf(proj_w[gid - 196608]);
  if (gid < 768)
    qkvb[gid] = (gid < 256) ? q_bias[gid] : ((gid < 512) ? 0.f : v_bias[gid - 512]);
}

// -------- X fp32 -> bf16 (plain row-major) + 16 zero pad rows ---------------
__global__ __launch_bounds__(256) void xbf16(
    const float* __restrict__ X, unsigned short* __restrict__ Xb)
{
  size_t gid = (size_t)blockIdx.x * 256 + threadIdx.x;   // 12546 blocks
  if (gid < 3211264) {
    const float4* xp = (const float4*)X;
    float4 f0 = xp[2 * gid], f1 = xp[2 * gid + 1];
    bf16x8 u;
    u[0] = (__bf16)f0.x; u[1] = (__bf16)f0.y; u[2] = (__bf16)f0.z; u[3] = (__bf16)f0.w;
    u[4] = (__bf16)f1.x; u[5] = (__bf16)f1.y; u[6] = (__bf16)f1.z; u[7] = (__bf16)f1.w;
    ((bf16x8*)Xb)[gid] = u;
  } else {
    bf16x8 z = {};
    ((bf16x8*)Xb)[gid] = z;                   // zero-pad rows 100352..100367
  }
}

// ---------------- CPB MLP: table16[r][h] = 16*sigmoid(mlp(tab[r])) ----------
__global__ __launch_bounds__(64) void cpb_mlp(
    const float* __restrict__ tab, const float* __restrict__ w1,
    const float* __restrict__ b1, const float* __restrict__ w2,
    float* __restrict__ table16)
{
  int r = blockIdx.x;            // 169 rows
  int t = threadIdx.x;           // 64 lanes
  float x0 = tab[r * 2 + 0], x1 = tab[r * 2 + 1];
  float part[8];
#pragma unroll
  for (int h = 0; h < 8; ++h) part[h] = 0.f;
  for (int j = t; j < 512; j += 64) {
    float hv = fmaxf(w1[j * 2 + 0] * x0 + w1[j * 2 + 1] * x1 + b1[j], 0.f);
#pragma unroll
    for (int h = 0; h < 8; ++h) part[h] += hv * w2[h * 512 + j];
  }
#pragma unroll
  for (int h = 0; h < 8; ++h) {
    float v = part[h];
    for (int off = 32; off > 0; off >>= 1) v += __shfl_down(v, off, 64);
    if (t == 0) table16[r * 8 + h] = 16.f / (1.f + expf(-v));
  }
}

// -------- bias64[h][i][j] (8x64x64, -1e30 pad) and mask64 (0-pad), *log2(e)
__global__ __launch_bounds__(256) void bmb(
    const float* __restrict__ t16, const int* __restrict__ ridx,
    const float* __restrict__ mask, float* __restrict__ bias64,
    float* __restrict__ mask64)
{
  const float L2E = 1.44269504f;
  int gid = blockIdx.x * 256 + threadIdx.x;   // 1152 blocks = 294912 = 32768 + 262144
  int p = gid & 4095, i = p >> 6, j = p & 63;
  bool valid = (i < 49) && (j < 49);
  if (gid < 32768) {
    int h = gid >> 12;
    // -1e30 padding folds the attention mask for i>=49 / j>=49 rows/cols
    bias64[gid] = valid ? t16[ridx[i * 49 + j] * 8 + h] * L2E : -1e30f;
  } else {
    int g2 = gid - 32768;
    int w = g2 >> 12;
    mask64[g2] = valid ? mask[w * 2401 + i * 49 + j] * L2E : 0.f;
  }
}

// ============ FUSED QKV GEMM + window attention (8 waves, 1 head/wave) ======
// block = 1 window, 512 threads. sX staged once (32 KB, cp16, pre-swizzled
// source -> linear LDS). Per-wave LDS = 4 KB vT only. K/Q fragments are
// LANE-LOCAL conversions of the GEMM accumulators (the d' permutation makes
// the epilogue pack lane-local - no LDS bounce). P kept in registers and
// redistributed to PV fragments with cross-quad shuffles (same l15).
__global__ __launch_bounds__(512, 4) void qkv_attn(
    const unsigned short* __restrict__ Xb, const unsigned short* __restrict__ W,
    const float* __restrict__ qkvb, const float* __restrict__ logit_scale,
    const float* __restrict__ bias64, const float* __restrict__ mask64,
    unsigned short* __restrict__ aout)
{
  __shared__ __align__(1024) char smem[65536];
  const int t = threadIdx.x, w = t >> 6, l = t & 63, quad = l >> 4, l15 = l & 15;
  char* sX = smem;                          // [64 rows][512 B], kt-chunk swizzled
  char* vT = smem + 32768 + w * 4096;       // per-wave V^T scatter region
  const int win = blockIdx.x;               // 2048 windows
  const int wtok = win * 49;
  const unsigned short* xrow = Xb + (size_t)wtok * 256;
  const int h = w;                          // wave = head

  // ---- stage X window (rows >= 49 zeroed); wave w -> rows w*8 .. w*8+7 ----
  {
    const int r0 = w * 8;
    const int s = l & 31;                   // 16B slot within 512B row
#pragma unroll
    for (int seg = 0; seg < 4; ++seg) {
      const int row = r0 + 2 * seg + (l >> 5);
      if (row < 49) {
        const unsigned short* src = xrow + (size_t)row * 256
                                  + (s >> 3) * 64 + (((s & 7) ^ (row & 7)) * 8);
        cp16(src, sX + (r0 + 2 * seg) * 512);   // dest: uniform base + lane*16
      } else {
        uint4 z = {};
        *(uint4*)(sX + row * 512 + s * 16) = z;
      }
    }
  }
  __syncthreads();

  // GEMM: M=64 tokens (sX), N=32 head dims (global W), K=256.
  // acc[nt][mA]: lane l15 -> token mA*16+l15 ; quad*4+r -> d = nt*16+quad*4+r.
  auto do_gemm = [&](int wrb, f32x4 (&acc)[2][4]) {
#pragma unroll
    for (int kt = 0; kt < 4; ++kt)
#pragma unroll
      for (int kk = 0; kk < 2; ++kk) {
        const int co = kt * 64 + (4 * kk + quad) * 8;
        bf16x8 wf[2], xf[4];
#pragma unroll
        for (int nt = 0; nt < 2; ++nt)
          wf[nt] = *(const bf16x8*)(W + (size_t)(wrb + nt * 16 + l15) * 256 + co);
#pragma unroll
        for (int mA = 0; mA < 4; ++mA)
          xf[mA] = *(const bf16x8*)(sX + (mA * 16 + l15) * 512 + kt * 128
                                       + (((4 * kk + quad) ^ (l15 & 7)) * 16));
#pragma unroll
        for (int nt = 0; nt < 2; ++nt)
#pragma unroll
          for (int mA = 0; mA < 4; ++mA)
            acc[nt][mA] = __builtin_amdgcn_mfma_f32_16x16x32_bf16(wf[nt], xf[mA], acc[nt][mA], 0, 0, 0);
      }
  };

  // lane-local acc(+bias) -> d'-fragment conversion (no LDS!)
  auto cvt_frag = [&](f32x4 (&acc)[2][4], const float* bias, bf16x8 (&f)[4]) {
    const f32x4 b0 = *(const f32x4*)(bias + quad * 4);
    const f32x4 b1 = *(const f32x4*)(bias + 16 + quad * 4);
#pragma unroll
    for (int mt = 0; mt < 4; ++mt) {
      f[mt][0] = (__bf16)(acc[0][mt][0] + b0[0]); f[mt][1] = (__bf16)(acc[0][mt][1] + b0[1]);
      f[mt][2] = (__bf16)(acc[0][mt][2] + b0[2]); f[mt][3] = (__bf16)(acc[0][mt][3] + b0[3]);
      f[mt][4] = (__bf16)(acc[1][mt][0] + b1[0]); f[mt][5] = (__bf16)(acc[1][mt][1] + b1[1]);
      f[mt][6] = (__bf16)(acc[1][mt][2] + b1[2]); f[mt][7] = (__bf16)(acc[1][mt][3] + b1[3]);
    }
  };

  // ---- K and Q GEMMs -> in-register fragments ----
  bf16x8 kf[4], qf[4];
  {
    f32x4 ka[2][4] = {};
    do_gemm(256 + h * 32, ka);
    cvt_frag(ka, qkvb + 256 + h * 32, kf);
  }
  {
    f32x4 qa[2][4] = {};
    do_gemm(h * 32, qa);
    cvt_frag(qa, qkvb + h * 32, qf);
  }

  // ---- S^T[j][i] = K . Q^T ----
  f32x4 sacc[4][4] = {};
  __builtin_amdgcn_s_setprio(1);
#pragma unroll
  for (int mt = 0; mt < 4; ++mt)
#pragma unroll
    for (int nt = 0; nt < 4; ++nt)
      sacc[mt][nt] = __builtin_amdgcn_mfma_f32_16x16x32_bf16(kf[mt], qf[nt], sacc[mt][nt], 0, 0, 0);
  __builtin_amdgcn_s_setprio(0);

  // ---- norms (perm-invariant); log2(e) folded into rqv ----
  const float scale = __expf(fminf(logit_scale[h], 4.60517019f)) * 1.44269504f;
  float rqv[4];
#pragma unroll
  for (int nt = 0; nt < 4; ++nt) {
    float s = 0.f;
#pragma unroll
    for (int d = 0; d < 8; ++d) { float f = (float)qf[nt][d]; s += f * f; }
    s += __shfl_xor(s, 16, 64); s += __shfl_xor(s, 32, 64);
    rqv[nt] = scale / fmaxf(sqrtf(s), 1e-12f);
  }
  float rkl[4];
#pragma unroll
  for (int mt = 0; mt < 4; ++mt) {
    float s = 0.f;
#pragma unroll
    for (int d = 0; d < 8; ++d) { float f = (float)kf[mt][d]; s += f * f; }
    s += __shfl_xor(s, 16, 64); s += __shfl_xor(s, 32, 64);
    rkl[mt] = 1.f / fmaxf(sqrtf(s), 1e-12f);
  }
  f32x4 rk4v[4];
#pragma unroll
  for (int mt = 0; mt < 4; ++mt)
#pragma unroll
    for (int r = 0; r < 4; ++r)
      rk4v[mt][r] = __shfl(rkl[mt], (quad << 2) + r, 16);

  // ---- V GEMM -> vT scatter (true-d rows, swizzled) ----
  {
    f32x4 va[2][4] = {};
    do_gemm(512 + h * 32, va);
    const f32x4 vb0 = *(const f32x4*)(qkvb + 512 + h * 32 + quad * 4);
    const f32x4 vb1 = *(const f32x4*)(qkvb + 512 + h * 32 + 16 + quad * 4);
#pragma unroll
    for (int mA = 0; mA < 4; ++mA) {
      const int tok = mA * 16 + l15;
#pragma unroll
      for (int nt = 0; nt < 2; ++nt) {
#pragma unroll
        for (int r = 0; r < 4; ++r) {
          const int d = nt * 16 + quad * 4 + r;
          *(__bf16*)(vT + d * 128 + (((tok >> 3) ^ (d & 7)) << 4) + (tok & 7) * 2) =
              (__bf16)(va[nt][mA][r] + (nt ? vb1[r] : vb0[r]));
        }
      }
    }
  }

  // ---- softmax (log2 domain) -> pk2 in registers (hides vT scatter) ----
  // pk2[nt][mt] = 2 u32 of bf16{p[0],p[1]},{p[2],p[3]} for i=nt*16+l15,
  // j = mt*16 + quad*4 + r.
  const float* bh = bias64 + (size_t)h * 4096;
  const float* mw = mask64 + (size_t)(win & 63) * 4096;
  uint2 pk2[4][4];
  float rs4[4];
#pragma unroll
  for (int nt = 0; nt < 4; ++nt) {
    const int i = nt * 16 + l15;
    const float rqi = rqv[nt];
    float mx = -3e38f;
#pragma unroll
    for (int mt = 0; mt < 4; ++mt) {
      const int jb = mt * 16 + quad * 4;
      const f32x4 b4 = *(const f32x4*)(bh + i * 64 + jb);
      const f32x4 m4 = *(const f32x4*)(mw + i * 64 + jb);
#pragma unroll
      for (int r = 0; r < 4; ++r) {
        float sv = fmaf(sacc[mt][nt][r], rqi * rk4v[mt][r], b4[r] + m4[r]);
        sacc[mt][nt][r] = sv;
        mx = fmaxf(mx, sv);
      }
    }
    mx = fmaxf(mx, __shfl_xor(mx, 16, 64));
    mx = fmaxf(mx, __shfl_xor(mx, 32, 64));
    float sum = 0.f;
#pragma unroll
    for (int mt = 0; mt < 4; ++mt) {
      float pv[4];
#pragma unroll
      for (int r = 0; r < 4; ++r) {
        pv[r] = __builtin_amdgcn_exp2f(sacc[mt][nt][r] - mx);
        sum += pv[r];
      }
      bf16x4 pk;
      pk[0] = (__bf16)pv[0]; pk[1] = (__bf16)pv[1];
      pk[2] = (__bf16)pv[2]; pk[3] = (__bf16)pv[3];
      pk2[nt][mt] = *(uint2*)&pk;
    }
    sum += __shfl_xor(sum, 16, 64);
    sum += __shfl_xor(sum, 32, 64);
    rs4[nt] = 1.f / sum;                    // normalization deferred to O store
  }

  // ---- vT drain, load vf ----
  asm volatile("s_waitcnt lgkmcnt(0)" ::: "memory");
  __builtin_amdgcn_sched_barrier(0);
  bf16x8 vf[2][2];
#pragma unroll
  for (int kk = 0; kk < 2; ++kk)
#pragma unroll
    for (int mt = 0; mt < 2; ++mt)
      vf[kk][mt] = *(const bf16x8*)(vT + (mt * 16 + l15) * 128
                                       + (((4 * kk + quad) ^ (l15 & 7)) * 16));

  // ---- O^T[d][i] = V^T . P^T ; pf built by cross-quad shuffles ----
  // pf[kk][nt] lane (l15,quad) needs P[i=nt*16+l15][j=32kk+8quad+s], s=0..7:
  // low 4 from lane l15+32(quad&1) (its pk2[nt][2kk+(quad>>1)]), high 4 from
  // lane l15+32(quad&1)+16 (same mt).
  const int srcA = l15 + 32 * (quad & 1);
  const bool hiSel = (quad >> 1) != 0;
  f32x4 oacc[2][4] = {};
#pragma unroll
  for (int kk = 0; kk < 2; ++kk) {
    bf16x8 pf[4];
#pragma unroll
    for (int nt = 0; nt < 4; ++nt) {
      const uint2 e = pk2[nt][2 * kk], o = pk2[nt][2 * kk + 1];
      unsigned e0 = __shfl((int)e.x, srcA, 64),      e1 = __shfl((int)e.y, srcA, 64);
      unsigned o0 = __shfl((int)o.x, srcA, 64),      o1 = __shfl((int)o.y, srcA, 64);
      unsigned e2 = __shfl((int)e.x, srcA + 16, 64), e3 = __shfl((int)e.y, srcA + 16, 64);
      unsigned o2 = __shfl((int)o.x, srcA + 16, 64), o3 = __shfl((int)o.y, srcA + 16, 64);
      uint4 u;
      u.x = hiSel ? o0 : e0; u.y = hiSel ? o1 : e1;
      u.z = hiSel ? o2 : e2; u.w = hiSel ? o3 : e3;
      pf[nt] = *(bf16x8*)&u;
    }
    __builtin_amdgcn_s_setprio(1);
#pragma unroll
    for (int mt = 0; mt < 2; ++mt)
#pragma unroll
      for (int nt = 0; nt < 4; ++nt)
        oacc[mt][nt] = __builtin_amdgcn_mfma_f32_16x16x32_bf16(vf[kk][mt], pf[nt], oacc[mt][nt], 0, 0, 0);
    __builtin_amdgcn_s_setprio(0);
  }

  // ---- store O (tok = nt*16+l15, d = mt*16+quad*4+r), rs applied here ----
#pragma unroll
  for (int nt = 0; nt < 4; ++nt) {
    const int tok = nt * 16 + l15;
    if (tok < 49) {
      unsigned short* op = aout + (size_t)(wtok + tok) * 256 + h * 32;
      const float rs = rs4[nt];
#pragma unroll
      for (int mt = 0; mt < 2; ++mt) {
        bf16x4 ov;
        ov[0] = (__bf16)(oacc[mt][nt][0] * rs); ov[1] = (__bf16)(oacc[mt][nt][1] * rs);
        ov[2] = (__bf16)(oacc[mt][nt][2] * rs); ov[3] = (__bf16)(oacc[mt][nt][3] * rs);
        *(bf16x4*)(op + mt * 16 + quad * 4) = ov;
      }
    }
  }
}

// ---------------- proj GEMM: bf16 A/W, fp32 out, packed f32x4 stores --------
__global__ __launch_bounds__(256) void gemm_proj(
    const unsigned short* __restrict__ A, const unsigned short* __restrict__ W,
    const float* __restrict__ bias, float* __restrict__ Y)
{
  __shared__ __align__(1024) unsigned short sA[128 * 64];
  __shared__ __align__(1024) unsigned short sB[128 * 64];
  const int t = threadIdx.x, w = t >> 6, l = t & 63, quad = l >> 4, l15 = l & 15;
  const int bm = blockIdx.y * 128, bn = blockIdx.x * 128;
  const int wm = (w >> 1) * 64, wn = (w & 1) * 64;
  const int srow = t >> 3, sch = t & 7;
  const int sc = sch ^ (srow & 7);

  f32x4 acc[4][4] = {};                      // acc[nW][mA]
  for (int kt = 0; kt < 4; ++kt) {
    const int k0 = kt << 6;
    if (kt) __syncthreads();
#pragma unroll
    for (int i = 0; i < 4; ++i) {
      const int row = i * 32 + srow;
      cp16(A + (size_t)(bm + row) * 256 + k0 + sc * 8, sA + (i * 256 + w * 64) * 8);
      cp16(W + (size_t)(bn + row) * 256 + k0 + sc * 8, sB + (i * 256 + w * 64) * 8);
    }
    __syncthreads();
#pragma unroll
    for (int kk = 0; kk < 2; ++kk) {
      bf16x8 xf[4], wf[4];
#pragma unroll
      for (int mt = 0; mt < 4; ++mt)
        xf[mt] = *(const bf16x8*)&sA[(wm + mt * 16 + l15) * 64 + (((4 * kk + quad) ^ (l15 & 7)) * 8)];
#pragma unroll
      for (int nt = 0; nt < 4; ++nt)
        wf[nt] = *(const bf16x8*)&sB[(wn + nt * 16 + l15) * 64 + (((4 * kk + quad) ^ (l15 & 7)) * 8)];
#pragma unroll
      for (int nt = 0; nt < 4; ++nt)
#pragma unroll
        for (int mt = 0; mt < 4; ++mt)
          acc[nt][mt] = __builtin_amdgcn_mfma_f32_16x16x32_bf16(wf[nt], xf[mt], acc[nt][mt], 0, 0, 0);
    }
  }
  // epilogue: lane holds 4 consecutive cols -> f32x4 16B stores
#pragma unroll
  for (int mA = 0; mA < 4; ++mA) {
    const int row = bm + wm + mA * 16 + l15;
    float* orow = Y + (size_t)row * 256;
#pragma unroll
    for (int nW = 0; nW < 4; ++nW) {
      const int c0 = bn + wn + nW * 16 + quad * 4;
      const f32x4 bv = *(const f32x4*)(bias + c0);
      f32x4 v = acc[nW][mA];
      v[0] += bv[0]; v[1] += bv[1]; v[2] += bv[2]; v[3] += bv[3];
      *(f32x4*)(orow + c0) = v;
    }
  }
}

// ---------------------------------------------------------------------------
extern "C" void kernel_launch(void* const* d_in, const int* in_sizes, int n_in,
                              void* d_out, int out_size, void* d_ws, size_t ws_size,
                              hipStream_t stream) {
  const float* x           = (const float*)d_in[0];
  const float* mask        = (const float*)d_in[1];
  const float* qkv_w       = (const float*)d_in[2];
  const float* q_bias      = (const float*)d_in[3];
  const float* v_bias      = (const float*)d_in[4];
  const float* logit_scale = (const float*)d_in[5];
  const float* cpb_w1      = (const float*)d_in[6];
  const float* cpb_b1      = (const float*)d_in[7];
  const float* cpb_w2      = (const float*)d_in[8];
  const float* proj_w      = (const float*)d_in[9];
  const float* proj_b      = (const float*)d_in[10];
  const float* rel_tab     = (const float*)d_in[11];
  const int*   rel_idx     = (const int*)d_in[12];
  float*       out         = (float*)d_out;

  char* ws = (char*)d_ws;
  unsigned short* xbf     = (unsigned short*)(ws + 0);          // 51388416 (bf16 X + pad)
  unsigned short* aows    = (unsigned short*)(ws + 154140672);  // 51380224
  unsigned short* wq      = (unsigned short*)(ws + 205520896);  // 393216
  unsigned short* wp      = (unsigned short*)(ws + 205914112);  // 131072
  float*          qkvb    = (float*)(ws + 206045184);           // 3072
  float*          table16 = (float*)(ws + 206048256);           // 5632
  float*          bias64  = (float*)(ws + 206053888);           // 131072
  float*          mask64  = (float*)(ws + 206184960);           // 1048576
  // end: 207233536

  prep_kernel<<<1024, 256, 0, stream>>>(qkv_w, proj_w, q_bias, v_bias, wq, wp, qkvb);
  cpb_mlp<<<169, 64, 0, stream>>>(rel_tab, cpb_w1, cpb_b1, cpb_w2, table16);
  bmb<<<1152, 256, 0, stream>>>(table16, rel_idx, mask, bias64, mask64);
  xbf16<<<12546, 256, 0, stream>>>(x, xbf);
  qkv_attn<<<2048, 512, 0, stream>>>(xbf, wq, qkvb, logit_scale, bias64, mask64, aows);
  gemm_proj<<<dim3(2, 784), 256, 0, stream>>>(aows, wp, proj_b, out);
}

// Round 8
// 455.397 us; speedup vs baseline: 1.8525x; 1.0031x over previous
//
#include <hip/hip_runtime.h>

#define DEV __device__ __forceinline__

typedef float  f32x4  __attribute__((ext_vector_type(4)));
typedef __bf16 bf16x4 __attribute__((ext_vector_type(4)));
typedef __bf16 bf16x8 __attribute__((ext_vector_type(8)));

DEV unsigned short f2bf(float f) {
  unsigned u = __float_as_uint(f);
  u += 0x7fffu + ((u >> 16) & 1u);           // round-to-nearest-even
  return (unsigned short)(u >> 16);
}

DEV void cp16(const void* g, void* l) {      // async global->LDS, 16B/lane
  __builtin_amdgcn_global_load_lds((const __attribute__((address_space(1))) void*)g,
                                   (__attribute__((address_space(3))) void*)l, 16, 0, 0);
}

// ---------------- prep: weights fp32->bf16 + qkv bias assembly --------------
__global__ __launch_bounds__(256) void prep_kernel(
    const float* __restrict__ qkv_w, const float* __restrict__ proj_w,
    const float* __restrict__ q_bias, const float* __restrict__ v_bias,
    unsigned short* __restrict__ wq, unsigned short* __restrict__ wp,
    float* __restrict__ qkvb)
{
  int gid = blockIdx.x * 256 + threadIdx.x;     // 1024 blocks -> 262144 = 196608+65536
  if (gid < 196608) wq[gid] = f2bf(qkv_w[gid]);
  else              wp[gid - 196608] = f2bf(proj_w[gid - 196608]);
  if (gid < 768)
    qkvb[gid] = (gid < 256) ? q_bias[gid] : ((gid < 512) ? 0.f : v_bias[gid - 512]);
}

// -------- X fp32 -> bf16 (plain row-major) + 16 zero pad rows ---------------
__global__ __launch_bounds__(256) void xbf16(
    const float* __restrict__ X, unsigned short* __restrict__ Xb)
{
  size_t gid = (size_t)blockIdx.x * 256 + threadIdx.x;   // 12546 blocks
  if (gid < 3211264) {
    const float4* xp = (const float4*)X;
    float4 f0 = xp[2 * gid], f1 = xp[2 * gid + 1];
    bf16x8 u;
    u[0] = (__bf16)f0.x; u[1] = (__bf16)f0.y; u[2] = (__bf16)f0.z; u[3] = (__bf16)f0.w;
    u[4] = (__bf16)f1.x; u[5] = (__bf16)f1.y; u[6] = (__bf16)f1.z; u[7] = (__bf16)f1.w;
    ((bf16x8*)Xb)[gid] = u;
  } else {
    bf16x8 z = {};
    ((bf16x8*)Xb)[gid] = z;                   // zero-pad rows 100352..100367
  }
}

// ---------------- CPB MLP: table16[r][h] = 16*sigmoid(mlp(tab[r])) ----------
__global__ __launch_bounds__(64) void cpb_mlp(
    const float* __restrict__ tab, const float* __restrict__ w1,
    const float* __restrict__ b1, const float* __restrict__ w2,
    float* __restrict__ table16)
{
  int r = blockIdx.x;            // 169 rows
  int t = threadIdx.x;           // 64 lanes
  float x0 = tab[r * 2 + 0], x1 = tab[r * 2 + 1];
  float part[8];
#pragma unroll
  for (int h = 0; h < 8; ++h) part[h] = 0.f;
  for (int j = t; j < 512; j += 64) {
    float hv = fmaxf(w1[j * 2 + 0] * x0 + w1[j * 2 + 1] * x1 + b1[j], 0.f);
#pragma unroll
    for (int h = 0; h < 8; ++h) part[h] += hv * w2[h * 512 + j];
  }
#pragma unroll
  for (int h = 0; h < 8; ++h) {
    float v = part[h];
    for (int off = 32; off > 0; off >>= 1) v += __shfl_down(v, off, 64);
    if (t == 0) table16[r * 8 + h] = 16.f / (1.f + expf(-v));
  }
}

// -------- bias64[h][i][j] (8x64x64, -1e30 pad) and mask64 (0-pad), *log2(e)
__global__ __launch_bounds__(256) void bmb(
    const float* __restrict__ t16, const int* __restrict__ ridx,
    const float* __restrict__ mask, float* __restrict__ bias64,
    float* __restrict__ mask64)
{
  const float L2E = 1.44269504f;
  int gid = blockIdx.x * 256 + threadIdx.x;   // 1152 blocks = 294912 = 32768 + 262144
  int p = gid & 4095, i = p >> 6, j = p & 63;
  bool valid = (i < 49) && (j < 49);
  if (gid < 32768) {
    int h = gid >> 12;
    // -1e30 padding folds the attention mask for i>=49 / j>=49 rows/cols
    bias64[gid] = valid ? t16[ridx[i * 49 + j] * 8 + h] * L2E : -1e30f;
  } else {
    int g2 = gid - 32768;
    int w = g2 >> 12;
    mask64[g2] = valid ? mask[w * 2401 + i * 49 + j] * L2E : 0.f;
  }
}

// ============ FUSED QKV GEMM + window attention (8 waves, 1 head/wave) ======
// block = 1 window, 512 threads. sX staged once (32 KB cp16). Per-wave LDS =
// 4 KB vT only. K/Q fragments lane-local from GEMM accs. P in registers,
// redistributed by cross-quad shuffles. O written HEAD-PACKED [win][h][tok][32]
// -> each wave writes a dense 3136B region: no write amplification.
__global__ __launch_bounds__(512, 4) void qkv_attn(
    const unsigned short* __restrict__ Xb, const unsigned short* __restrict__ W,
    const float* __restrict__ qkvb, const float* __restrict__ logit_scale,
    const float* __restrict__ bias64, const float* __restrict__ mask64,
    unsigned short* __restrict__ aout)
{
  __shared__ __align__(1024) char smem[65536];
  const int t = threadIdx.x, w = t >> 6, l = t & 63, quad = l >> 4, l15 = l & 15;
  char* sX = smem;                          // [64 rows][512 B], kt-chunk swizzled
  char* vT = smem + 32768 + w * 4096;       // per-wave V^T scatter region
  const int win = blockIdx.x;               // 2048 windows
  const int wtok = win * 49;
  const unsigned short* xrow = Xb + (size_t)wtok * 256;
  const int h = w;                          // wave = head

  // ---- stage X window (rows >= 49 zeroed); wave w -> rows w*8 .. w*8+7 ----
  {
    const int r0 = w * 8;
    const int s = l & 31;                   // 16B slot within 512B row
#pragma unroll
    for (int seg = 0; seg < 4; ++seg) {
      const int row = r0 + 2 * seg + (l >> 5);
      if (row < 49) {
        const unsigned short* src = xrow + (size_t)row * 256
                                  + (s >> 3) * 64 + (((s & 7) ^ (row & 7)) * 8);
        cp16(src, sX + (r0 + 2 * seg) * 512);   // dest: uniform base + lane*16
      } else {
        uint4 z = {};
        *(uint4*)(sX + row * 512 + s * 16) = z;
      }
    }
  }
  __syncthreads();

  // GEMM: M=64 tokens (sX), N=32 head dims (global W), K=256.
  // acc[nt][mA]: lane l15 -> token mA*16+l15 ; quad*4+r -> d = nt*16+quad*4+r.
  auto do_gemm = [&](int wrb, f32x4 (&acc)[2][4]) {
#pragma unroll
    for (int kt = 0; kt < 4; ++kt)
#pragma unroll
      for (int kk = 0; kk < 2; ++kk) {
        const int co = kt * 64 + (4 * kk + quad) * 8;
        bf16x8 wf[2], xf[4];
#pragma unroll
        for (int nt = 0; nt < 2; ++nt)
          wf[nt] = *(const bf16x8*)(W + (size_t)(wrb + nt * 16 + l15) * 256 + co);
#pragma unroll
        for (int mA = 0; mA < 4; ++mA)
          xf[mA] = *(const bf16x8*)(sX + (mA * 16 + l15) * 512 + kt * 128
                                       + (((4 * kk + quad) ^ (l15 & 7)) * 16));
#pragma unroll
        for (int nt = 0; nt < 2; ++nt)
#pragma unroll
          for (int mA = 0; mA < 4; ++mA)
            acc[nt][mA] = __builtin_amdgcn_mfma_f32_16x16x32_bf16(wf[nt], xf[mA], acc[nt][mA], 0, 0, 0);
      }
  };

  // lane-local acc(+bias) -> d'-fragment conversion (no LDS!)
  auto cvt_frag = [&](f32x4 (&acc)[2][4], const float* bias, bf16x8 (&f)[4]) {
    const f32x4 b0 = *(const f32x4*)(bias + quad * 4);
    const f32x4 b1 = *(const f32x4*)(bias + 16 + quad * 4);
#pragma unroll
    for (int mt = 0; mt < 4; ++mt) {
      f[mt][0] = (__bf16)(acc[0][mt][0] + b0[0]); f[mt][1] = (__bf16)(acc[0][mt][1] + b0[1]);
      f[mt][2] = (__bf16)(acc[0][mt][2] + b0[2]); f[mt][3] = (__bf16)(acc[0][mt][3] + b0[3]);
      f[mt][4] = (__bf16)(acc[1][mt][0] + b1[0]); f[mt][5] = (__bf16)(acc[1][mt][1] + b1[1]);
      f[mt][6] = (__bf16)(acc[1][mt][2] + b1[2]); f[mt][7] = (__bf16)(acc[1][mt][3] + b1[3]);
    }
  };

  // ---- K and Q GEMMs -> in-register fragments ----
  bf16x8 kf[4], qf[4];
  {
    f32x4 ka[2][4] = {};
    do_gemm(256 + h * 32, ka);
    cvt_frag(ka, qkvb + 256 + h * 32, kf);
  }
  {
    f32x4 qa[2][4] = {};
    do_gemm(h * 32, qa);
    cvt_frag(qa, qkvb + h * 32, qf);
  }

  // ---- S^T[j][i] = K . Q^T ----
  f32x4 sacc[4][4] = {};
  __builtin_amdgcn_s_setprio(1);
#pragma unroll
  for (int mt = 0; mt < 4; ++mt)
#pragma unroll
    for (int nt = 0; nt < 4; ++nt)
      sacc[mt][nt] = __builtin_amdgcn_mfma_f32_16x16x32_bf16(kf[mt], qf[nt], sacc[mt][nt], 0, 0, 0);
  __builtin_amdgcn_s_setprio(0);

  // ---- norms (perm-invariant); log2(e) folded into rqv ----
  const float scale = __expf(fminf(logit_scale[h], 4.60517019f)) * 1.44269504f;
  float rqv[4];
#pragma unroll
  for (int nt = 0; nt < 4; ++nt) {
    float s = 0.f;
#pragma unroll
    for (int d = 0; d < 8; ++d) { float f = (float)qf[nt][d]; s += f * f; }
    s += __shfl_xor(s, 16, 64); s += __shfl_xor(s, 32, 64);
    rqv[nt] = scale / fmaxf(sqrtf(s), 1e-12f);
  }
  float rkl[4];
#pragma unroll
  for (int mt = 0; mt < 4; ++mt) {
    float s = 0.f;
#pragma unroll
    for (int d = 0; d < 8; ++d) { float f = (float)kf[mt][d]; s += f * f; }
    s += __shfl_xor(s, 16, 64); s += __shfl_xor(s, 32, 64);
    rkl[mt] = 1.f / fmaxf(sqrtf(s), 1e-12f);
  }
  f32x4 rk4v[4];
#pragma unroll
  for (int mt = 0; mt < 4; ++mt)
#pragma unroll
    for (int r = 0; r < 4; ++r)
      rk4v[mt][r] = __shfl(rkl[mt], (quad << 2) + r, 16);

  // ---- V GEMM -> vT scatter (true-d rows, swizzled) ----
  {
    f32x4 va[2][4] = {};
    do_gemm(512 + h * 32, va);
    const f32x4 vb0 = *(const f32x4*)(qkvb + 512 + h * 32 + quad * 4);
    const f32x4 vb1 = *(const f32x4*)(qkvb + 512 + h * 32 + 16 + quad * 4);
#pragma unroll
    for (int mA = 0; mA < 4; ++mA) {
      const int tok = mA * 16 + l15;
#pragma unroll
      for (int nt = 0; nt < 2; ++nt) {
#pragma unroll
        for (int r = 0; r < 4; ++r) {
          const int d = nt * 16 + quad * 4 + r;
          *(__bf16*)(vT + d * 128 + (((tok >> 3) ^ (d & 7)) << 4) + (tok & 7) * 2) =
              (__bf16)(va[nt][mA][r] + (nt ? vb1[r] : vb0[r]));
        }
      }
    }
  }

  // ---- softmax (log2 domain) -> pk2 in registers (hides vT scatter) ----
  const float* bh = bias64 + (size_t)h * 4096;
  const float* mw = mask64 + (size_t)(win & 63) * 4096;
  uint2 pk2[4][4];
  float rs4[4];
#pragma unroll
  for (int nt = 0; nt < 4; ++nt) {
    const int i = nt * 16 + l15;
    const float rqi = rqv[nt];
    float mx = -3e38f;
#pragma unroll
    for (int mt = 0; mt < 4; ++mt) {
      const int jb = mt * 16 + quad * 4;
      const f32x4 b4 = *(const f32x4*)(bh + i * 64 + jb);
      const f32x4 m4 = *(const f32x4*)(mw + i * 64 + jb);
#pragma unroll
      for (int r = 0; r < 4; ++r) {
        float sv = fmaf(sacc[mt][nt][r], rqi * rk4v[mt][r], b4[r] + m4[r]);
        sacc[mt][nt][r] = sv;
        mx = fmaxf(mx, sv);
      }
    }
    mx = fmaxf(mx, __shfl_xor(mx, 16, 64));
    mx = fmaxf(mx, __shfl_xor(mx, 32, 64));
    float sum = 0.f;
#pragma unroll
    for (int mt = 0; mt < 4; ++mt) {
      float pv[4];
#pragma unroll
      for (int r = 0; r < 4; ++r) {
        pv[r] = __builtin_amdgcn_exp2f(sacc[mt][nt][r] - mx);
        sum += pv[r];
      }
      bf16x4 pk;
      pk[0] = (__bf16)pv[0]; pk[1] = (__bf16)pv[1];
      pk[2] = (__bf16)pv[2]; pk[3] = (__bf16)pv[3];
      pk2[nt][mt] = *(uint2*)&pk;
    }
    sum += __shfl_xor(sum, 16, 64);
    sum += __shfl_xor(sum, 32, 64);
    rs4[nt] = 1.f / sum;                    // normalization deferred to O store
  }

  // ---- vT drain, load vf ----
  asm volatile("s_waitcnt lgkmcnt(0)" ::: "memory");
  __builtin_amdgcn_sched_barrier(0);
  bf16x8 vf[2][2];
#pragma unroll
  for (int kk = 0; kk < 2; ++kk)
#pragma unroll
    for (int mt = 0; mt < 2; ++mt)
      vf[kk][mt] = *(const bf16x8*)(vT + (mt * 16 + l15) * 128
                                       + (((4 * kk + quad) ^ (l15 & 7)) * 16));

  // ---- O^T[d][i] = V^T . P^T ; pf built by cross-quad shuffles ----
  const int srcA = l15 + 32 * (quad & 1);
  const bool hiSel = (quad >> 1) != 0;
  f32x4 oacc[2][4] = {};
#pragma unroll
  for (int kk = 0; kk < 2; ++kk) {
    bf16x8 pf[4];
#pragma unroll
    for (int nt = 0; nt < 4; ++nt) {
      const uint2 e = pk2[nt][2 * kk], o = pk2[nt][2 * kk + 1];
      unsigned e0 = __shfl((int)e.x, srcA, 64),      e1 = __shfl((int)e.y, srcA, 64);
      unsigned o0 = __shfl((int)o.x, srcA, 64),      o1 = __shfl((int)o.y, srcA, 64);
      unsigned e2 = __shfl((int)e.x, srcA + 16, 64), e3 = __shfl((int)e.y, srcA + 16, 64);
      unsigned o2 = __shfl((int)o.x, srcA + 16, 64), o3 = __shfl((int)o.y, srcA + 16, 64);
      uint4 u;
      u.x = hiSel ? o0 : e0; u.y = hiSel ? o1 : e1;
      u.z = hiSel ? o2 : e2; u.w = hiSel ? o3 : e3;
      pf[nt] = *(bf16x8*)&u;
    }
    __builtin_amdgcn_s_setprio(1);
#pragma unroll
    for (int mt = 0; mt < 2; ++mt)
#pragma unroll
      for (int nt = 0; nt < 4; ++nt)
        oacc[mt][nt] = __builtin_amdgcn_mfma_f32_16x16x32_bf16(vf[kk][mt], pf[nt], oacc[mt][nt], 0, 0, 0);
    __builtin_amdgcn_s_setprio(0);
  }

  // ---- store O head-packed: aout[(win*8+h)*1568 + tok*32 + d] (dense/wave)
  unsigned short* ob = aout + (size_t)(win * 8 + h) * 1568;
#pragma unroll
  for (int nt = 0; nt < 4; ++nt) {
    const int tok = nt * 16 + l15;
    if (tok < 49) {
      unsigned short* op = ob + tok * 32;
      const float rs = rs4[nt];
#pragma unroll
      for (int mt = 0; mt < 2; ++mt) {
        bf16x4 ov;
        ov[0] = (__bf16)(oacc[mt][nt][0] * rs); ov[1] = (__bf16)(oacc[mt][nt][1] * rs);
        ov[2] = (__bf16)(oacc[mt][nt][2] * rs); ov[3] = (__bf16)(oacc[mt][nt][3] * rs);
        *(bf16x4*)(op + mt * 16 + quad * 4) = ov;
      }
    }
  }
}

// ---------------- proj GEMM: A gathered from head-packed aows ---------------
// A row g (token) col c lives at aows[((g/49)*8 + (c>>5))*1568 + (g%49)*32
// + (c&31)]. cp16's global source is per-lane -> the gather is free; the LDS
// dest stays linear (identical to before).
__global__ __launch_bounds__(256) void gemm_proj(
    const unsigned short* __restrict__ A, const unsigned short* __restrict__ W,
    const float* __restrict__ bias, float* __restrict__ Y)
{
  __shared__ __align__(1024) unsigned short sA[128 * 64];
  __shared__ __align__(1024) unsigned short sB[128 * 64];
  const int t = threadIdx.x, w = t >> 6, l = t & 63, quad = l >> 4, l15 = l & 15;
  const int bm = blockIdx.y * 128, bn = blockIdx.x * 128;
  const int wm = (w >> 1) * 64, wn = (w & 1) * 64;
  const int srow = t >> 3, sch = t & 7;
  const int sc = sch ^ (srow & 7);

  // per-lane A gather bases (per i-chunk): row g = bm + i*32 + srow
  size_t abase[4];
#pragma unroll
  for (int i = 0; i < 4; ++i) {
    const int g = bm + i * 32 + srow;
    const unsigned wn_ = (unsigned)(((unsigned long long)g * 87652394ull) >> 32); // g/49
    const int tok = g - (int)wn_ * 49;
    abase[i] = ((size_t)wn_ * 8 + (sc >> 2)) * 1568 + (size_t)tok * 32 + (sc & 3) * 8;
  }

  f32x4 acc[4][4] = {};                      // acc[nW][mA]
  for (int kt = 0; kt < 4; ++kt) {
    const int k0 = kt << 6;
    if (kt) __syncthreads();
#pragma unroll
    for (int i = 0; i < 4; ++i) {
      const int row = i * 32 + srow;
      cp16(A + abase[i] + (size_t)kt * 2 * 1568, sA + (i * 256 + w * 64) * 8);
      cp16(W + (size_t)(bn + row) * 256 + k0 + sc * 8, sB + (i * 256 + w * 64) * 8);
    }
    __syncthreads();
#pragma unroll
    for (int kk = 0; kk < 2; ++kk) {
      bf16x8 xf[4], wf[4];
#pragma unroll
      for (int mt = 0; mt < 4; ++mt)
        xf[mt] = *(const bf16x8*)&sA[(wm + mt * 16 + l15) * 64 + (((4 * kk + quad) ^ (l15 & 7)) * 8)];
#pragma unroll
      for (int nt = 0; nt < 4; ++nt)
        wf[nt] = *(const bf16x8*)&sB[(wn + nt * 16 + l15) * 64 + (((4 * kk + quad) ^ (l15 & 7)) * 8)];
#pragma unroll
      for (int nt = 0; nt < 4; ++nt)
#pragma unroll
        for (int mt = 0; mt < 4; ++mt)
          acc[nt][mt] = __builtin_amdgcn_mfma_f32_16x16x32_bf16(wf[nt], xf[mt], acc[nt][mt], 0, 0, 0);
    }
  }
  // epilogue: lane holds 4 consecutive cols -> f32x4 16B stores
#pragma unroll
  for (int mA = 0; mA < 4; ++mA) {
    const int row = bm + wm + mA * 16 + l15;
    float* orow = Y + (size_t)row * 256;
#pragma unroll
    for (int nW = 0; nW < 4; ++nW) {
      const int c0 = bn + wn + nW * 16 + quad * 4;
      const f32x4 bv = *(const f32x4*)(bias + c0);
      f32x4 v = acc[nW][mA];
      v[0] += bv[0]; v[1] += bv[1]; v[2] += bv[2]; v[3] += bv[3];
      *(f32x4*)(orow + c0) = v;
    }
  }
}

// ---------------------------------------------------------------------------
extern "C" void kernel_launch(void* const* d_in, const int* in_sizes, int n_in,
                              void* d_out, int out_size, void* d_ws, size_t ws_size,
                              hipStream_t stream) {
  const float* x           = (const float*)d_in[0];
  const float* mask        = (const float*)d_in[1];
  const float* qkv_w       = (const float*)d_in[2];
  const float* q_bias      = (const float*)d_in[3];
  const float* v_bias      = (const float*)d_in[4];
  const float* logit_scale = (const float*)d_in[5];
  const float* cpb_w1      = (const float*)d_in[6];
  const float* cpb_b1      = (const float*)d_in[7];
  const float* cpb_w2      = (const float*)d_in[8];
  const float* proj_w      = (const float*)d_in[9];
  const float* proj_b      = (const float*)d_in[10];
  const float* rel_tab     = (const float*)d_in[11];
  const int*   rel_idx     = (const int*)d_in[12];
  float*       out         = (float*)d_out;

  char* ws = (char*)d_ws;
  unsigned short* xbf     = (unsigned short*)(ws + 0);          // 51388416 (bf16 X + pad)
  unsigned short* aows    = (unsigned short*)(ws + 154140672);  // 51380224 (head-packed)
  unsigned short* wq      = (unsigned short*)(ws + 205520896);  // 393216
  unsigned short* wp      = (unsigned short*)(ws + 205914112);  // 131072
  float*          qkvb    = (float*)(ws + 206045184);           // 3072
  float*          table16 = (float*)(ws + 206048256);           // 5632
  float*          bias64  = (float*)(ws + 206053888);           // 131072
  float*          mask64  = (float*)(ws + 206184960);           // 1048576
  // end: 207233536

  prep_kernel<<<1024, 256, 0, stream>>>(qkv_w, proj_w, q_bias, v_bias, wq, wp, qkvb);
  cpb_mlp<<<169, 64, 0, stream>>>(rel_tab, cpb_w1, cpb_b1, cpb_w2, table16);
  bmb<<<1152, 256, 0, stream>>>(table16, rel_idx, mask, bias64, mask64);
  xbf16<<<12546, 256, 0, stream>>>(x, xbf);
  qkv_attn<<<2048, 512, 0, stream>>>(xbf, wq, qkvb, logit_scale, bias64, mask64, aows);
  gemm_proj<<<dim3(2, 784), 256, 0, stream>>>(aows, wp, proj_b, out);
}

// Round 9
// 416.730 us; speedup vs baseline: 2.0243x; 1.0928x over previous
//
#include <hip/hip_runtime.h>

#define DEV __device__ __forceinline__

typedef float  f32x4  __attribute__((ext_vector_type(4)));
typedef __bf16 bf16x4 __attribute__((ext_vector_type(4)));
typedef __bf16 bf16x8 __attribute__((ext_vector_type(8)));

DEV unsigned short f2bf(float f) {
  unsigned u = __float_as_uint(f);
  u += 0x7fffu + ((u >> 16) & 1u);           // round-to-nearest-even
  return (unsigned short)(u >> 16);
}

DEV void cp16(const void* g, void* l) {      // async global->LDS, 16B/lane
  __builtin_amdgcn_global_load_lds((const __attribute__((address_space(1))) void*)g,
                                   (__attribute__((address_space(3))) void*)l, 16, 0, 0);
}

// ---------------- prep: weights fp32->bf16 + qkv bias assembly --------------
__global__ __launch_bounds__(256) void prep_kernel(
    const float* __restrict__ qkv_w, const float* __restrict__ proj_w,
    const float* __restrict__ q_bias, const float* __restrict__ v_bias,
    unsigned short* __restrict__ wq, unsigned short* __restrict__ wp,
    float* __restrict__ qkvb)
{
  int gid = blockIdx.x * 256 + threadIdx.x;     // 1024 blocks -> 262144 = 196608+65536
  if (gid < 196608) wq[gid] = f2bf(qkv_w[gid]);
  else              wp[gid - 196608] = f2bf(proj_w[gid - 196608]);
  if (gid < 768)
    qkvb[gid] = (gid < 256) ? q_bias[gid] : ((gid < 512) ? 0.f : v_bias[gid - 512]);
}

// -------- X fp32 -> bf16 (plain row-major) + 16 zero pad rows ---------------
__global__ __launch_bounds__(256) void xbf16(
    const float* __restrict__ X, unsigned short* __restrict__ Xb)
{
  size_t gid = (size_t)blockIdx.x * 256 + threadIdx.x;   // 12546 blocks
  if (gid < 3211264) {
    const float4* xp = (const float4*)X;
    float4 f0 = xp[2 * gid], f1 = xp[2 * gid + 1];
    bf16x8 u;
    u[0] = (__bf16)f0.x; u[1] = (__bf16)f0.y; u[2] = (__bf16)f0.z; u[3] = (__bf16)f0.w;
    u[4] = (__bf16)f1.x; u[5] = (__bf16)f1.y; u[6] = (__bf16)f1.z; u[7] = (__bf16)f1.w;
    ((bf16x8*)Xb)[gid] = u;
  } else {
    bf16x8 z = {};
    ((bf16x8*)Xb)[gid] = z;                   // zero-pad rows 100352..100367
  }
}

// ---------------- CPB MLP: table16[r][h] = 16*sigmoid(mlp(tab[r])) ----------
__global__ __launch_bounds__(64) void cpb_mlp(
    const float* __restrict__ tab, const float* __restrict__ w1,
    const float* __restrict__ b1, const float* __restrict__ w2,
    float* __restrict__ table16)
{
  int r = blockIdx.x;            // 169 rows
  int t = threadIdx.x;           // 64 lanes
  float x0 = tab[r * 2 + 0], x1 = tab[r * 2 + 1];
  float part[8];
#pragma unroll
  for (int h = 0; h < 8; ++h) part[h] = 0.f;
  for (int j = t; j < 512; j += 64) {
    float hv = fmaxf(w1[j * 2 + 0] * x0 + w1[j * 2 + 1] * x1 + b1[j], 0.f);
#pragma unroll
    for (int h = 0; h < 8; ++h) part[h] += hv * w2[h * 512 + j];
  }
#pragma unroll
  for (int h = 0; h < 8; ++h) {
    float v = part[h];
    for (int off = 32; off > 0; off >>= 1) v += __shfl_down(v, off, 64);
    if (t == 0) table16[r * 8 + h] = 16.f / (1.f + expf(-v));
  }
}

// -------- bias64[h][i][j] (8x64x64, -1e30 pad) and mask64 (0-pad), *log2(e)
__global__ __launch_bounds__(256) void bmb(
    const float* __restrict__ t16, const int* __restrict__ ridx,
    const float* __restrict__ mask, float* __restrict__ bias64,
    float* __restrict__ mask64)
{
  const float L2E = 1.44269504f;
  int gid = blockIdx.x * 256 + threadIdx.x;   // 1152 blocks = 294912 = 32768 + 262144
  int p = gid & 4095, i = p >> 6, j = p & 63;
  bool valid = (i < 49) && (j < 49);
  if (gid < 32768) {
    int h = gid >> 12;
    // -1e30 padding folds the attention mask for i>=49 / j>=49 rows/cols
    bias64[gid] = valid ? t16[ridx[i * 49 + j] * 8 + h] * L2E : -1e30f;
  } else {
    int g2 = gid - 32768;
    int w = g2 >> 12;
    mask64[g2] = valid ? mask[w * 2401 + i * 49 + j] * L2E : 0.f;
  }
}

// ============ FUSED QKV GEMM + window attention (8 waves, 1 head/wave) ======
// block = 1 window, 512 threads. sX staged once (32 KB cp16). Per-wave LDS =
// 4 KB vT. K/Q fragments lane-local from GEMM accs WITH THE L2-NORM FOLDED IN
// (pre-bf16) - rk4v/rqv registers and the softmax multiply disappear.
// launch_bounds(512,2): CUDA semantics (2nd arg = blocks/CU) -> 128-VGPR cap;
// (512,4) capped at 64 and spilled ~300 MB to scratch (r7/r8 counters).
__global__ __launch_bounds__(512, 2) void qkv_attn(
    const unsigned short* __restrict__ Xb, const unsigned short* __restrict__ W,
    const float* __restrict__ qkvb, const float* __restrict__ logit_scale,
    const float* __restrict__ bias64, const float* __restrict__ mask64,
    unsigned short* __restrict__ aout)
{
  __shared__ __align__(1024) char smem[65536];
  const int t = threadIdx.x, w = t >> 6, l = t & 63, quad = l >> 4, l15 = l & 15;
  char* sX = smem;                          // [64 rows][512 B], kt-chunk swizzled
  char* vT = smem + 32768 + w * 4096;       // per-wave V^T scatter region
  const int win = blockIdx.x;               // 2048 windows
  const unsigned short* xrow = Xb + (size_t)(win * 49) * 256;
  const int h = w;                          // wave = head

  // ---- stage X window (rows >= 49 zeroed); wave w -> rows w*8 .. w*8+7 ----
  {
    const int r0 = w * 8;
    const int s = l & 31;                   // 16B slot within 512B row
#pragma unroll
    for (int seg = 0; seg < 4; ++seg) {
      const int row = r0 + 2 * seg + (l >> 5);
      if (row < 49) {
        const unsigned short* src = xrow + (size_t)row * 256
                                  + (s >> 3) * 64 + (((s & 7) ^ (row & 7)) * 8);
        cp16(src, sX + (r0 + 2 * seg) * 512);   // dest: uniform base + lane*16
      } else {
        uint4 z = {};
        *(uint4*)(sX + row * 512 + s * 16) = z;
      }
    }
  }
  __syncthreads();

  // GEMM: M=64 tokens (sX), N=32 head dims (global W), K=256.
  // acc[nt][mA]: lane l15 -> token mA*16+l15 ; quad*4+r -> d = nt*16+quad*4+r.
  auto do_gemm = [&](int wrb, f32x4 (&acc)[2][4]) {
#pragma unroll
    for (int kt = 0; kt < 4; ++kt)
#pragma unroll
      for (int kk = 0; kk < 2; ++kk) {
        const int co = kt * 64 + (4 * kk + quad) * 8;
        bf16x8 wf[2], xf[4];
#pragma unroll
        for (int nt = 0; nt < 2; ++nt)
          wf[nt] = *(const bf16x8*)(W + (size_t)(wrb + nt * 16 + l15) * 256 + co);
#pragma unroll
        for (int mA = 0; mA < 4; ++mA)
          xf[mA] = *(const bf16x8*)(sX + (mA * 16 + l15) * 512 + kt * 128
                                       + (((4 * kk + quad) ^ (l15 & 7)) * 16));
#pragma unroll
        for (int nt = 0; nt < 2; ++nt)
#pragma unroll
          for (int mA = 0; mA < 4; ++mA)
            acc[nt][mA] = __builtin_amdgcn_mfma_f32_16x16x32_bf16(wf[nt], xf[mA], acc[nt][mA], 0, 0, 0);
      }
  };

  // lane-local acc(+bias) -> L2-NORMALIZED d'-fragment (norm folded pre-bf16)
  auto cvt_norm = [&](f32x4 (&acc)[2][4], const float* bias, float mul,
                      bf16x8 (&f)[4]) {
    const f32x4 b0 = *(const f32x4*)(bias + quad * 4);
    const f32x4 b1 = *(const f32x4*)(bias + 16 + quad * 4);
#pragma unroll
    for (int mt = 0; mt < 4; ++mt) {       // token mt*16+l15
      float v[8];
#pragma unroll
      for (int r = 0; r < 4; ++r) {
        v[r]     = acc[0][mt][r] + b0[r];
        v[4 + r] = acc[1][mt][r] + b1[r];
      }
      float ss = 0.f;
#pragma unroll
      for (int i = 0; i < 8; ++i) ss += v[i] * v[i];
      ss += __shfl_xor(ss, 16, 64); ss += __shfl_xor(ss, 32, 64);
      const float rn = mul / fmaxf(sqrtf(ss), 1e-12f);
#pragma unroll
      for (int i = 0; i < 8; ++i) f[mt][i] = (__bf16)(v[i] * rn);
    }
  };

  // ---- K and Q GEMMs -> normalized in-register fragments ----
  const float scale = __expf(fminf(logit_scale[h], 4.60517019f)) * 1.44269504f;
  bf16x8 kf[4], qf[4];
  {
    f32x4 ka[2][4] = {};
    do_gemm(256 + h * 32, ka);
    cvt_norm(ka, qkvb + 256 + h * 32, 1.f, kf);
  }
  {
    f32x4 qa[2][4] = {};
    do_gemm(h * 32, qa);
    cvt_norm(qa, qkvb + h * 32, scale, qf);   // scale*log2(e) folded into q
  }

  // ---- S^T[j][i] = K . Q^T  (already scaled, log2 domain) ----
  f32x4 sacc[4][4] = {};
  __builtin_amdgcn_s_setprio(1);
#pragma unroll
  for (int mt = 0; mt < 4; ++mt)
#pragma unroll
    for (int nt = 0; nt < 4; ++nt)
      sacc[mt][nt] = __builtin_amdgcn_mfma_f32_16x16x32_bf16(kf[mt], qf[nt], sacc[mt][nt], 0, 0, 0);
  __builtin_amdgcn_s_setprio(0);

  // ---- V GEMM -> vT scatter (true-d rows, swizzled) ----
  {
    f32x4 va[2][4] = {};
    do_gemm(512 + h * 32, va);
    const f32x4 vb0 = *(const f32x4*)(qkvb + 512 + h * 32 + quad * 4);
    const f32x4 vb1 = *(const f32x4*)(qkvb + 512 + h * 32 + 16 + quad * 4);
#pragma unroll
    for (int mA = 0; mA < 4; ++mA) {
      const int tok = mA * 16 + l15;
#pragma unroll
      for (int nt = 0; nt < 2; ++nt) {
#pragma unroll
        for (int r = 0; r < 4; ++r) {
          const int d = nt * 16 + quad * 4 + r;
          *(__bf16*)(vT + d * 128 + (((tok >> 3) ^ (d & 7)) << 4) + (tok & 7) * 2) =
              (__bf16)(va[nt][mA][r] + (nt ? vb1[r] : vb0[r]));
        }
      }
    }
  }

  // ---- softmax (log2 domain) -> pk2 in registers (hides vT scatter) ----
  const float* bh = bias64 + (size_t)h * 4096;
  const float* mw = mask64 + (size_t)(win & 63) * 4096;
  uint2 pk2[4][4];
  float rs4[4];
#pragma unroll
  for (int nt = 0; nt < 4; ++nt) {
    const int i = nt * 16 + l15;
    float mx = -3e38f;
#pragma unroll
    for (int mt = 0; mt < 4; ++mt) {
      const int jb = mt * 16 + quad * 4;
      const f32x4 b4 = *(const f32x4*)(bh + i * 64 + jb);
      const f32x4 m4 = *(const f32x4*)(mw + i * 64 + jb);
#pragma unroll
      for (int r = 0; r < 4; ++r) {
        float sv = sacc[mt][nt][r] + b4[r] + m4[r];
        sacc[mt][nt][r] = sv;
        mx = fmaxf(mx, sv);
      }
    }
    mx = fmaxf(mx, __shfl_xor(mx, 16, 64));
    mx = fmaxf(mx, __shfl_xor(mx, 32, 64));
    float sum = 0.f;
#pragma unroll
    for (int mt = 0; mt < 4; ++mt) {
      float pv[4];
#pragma unroll
      for (int r = 0; r < 4; ++r) {
        pv[r] = __builtin_amdgcn_exp2f(sacc[mt][nt][r] - mx);
        sum += pv[r];
      }
      bf16x4 pk;
      pk[0] = (__bf16)pv[0]; pk[1] = (__bf16)pv[1];
      pk[2] = (__bf16)pv[2]; pk[3] = (__bf16)pv[3];
      pk2[nt][mt] = *(uint2*)&pk;
    }
    sum += __shfl_xor(sum, 16, 64);
    sum += __shfl_xor(sum, 32, 64);
    rs4[nt] = 1.f / sum;                    // normalization deferred to O store
  }

  // ---- vT drain, load vf ----
  asm volatile("s_waitcnt lgkmcnt(0)" ::: "memory");
  __builtin_amdgcn_sched_barrier(0);
  bf16x8 vf[2][2];
#pragma unroll
  for (int kk = 0; kk < 2; ++kk)
#pragma unroll
    for (int mt = 0; mt < 2; ++mt)
      vf[kk][mt] = *(const bf16x8*)(vT + (mt * 16 + l15) * 128
                                       + (((4 * kk + quad) ^ (l15 & 7)) * 16));

  // ---- O^T[d][i] = V^T . P^T ; pf built by cross-quad shuffles ----
  const int srcA = l15 + 32 * (quad & 1);
  const bool hiSel = (quad >> 1) != 0;
  f32x4 oacc[2][4] = {};
#pragma unroll
  for (int kk = 0; kk < 2; ++kk) {
    bf16x8 pf[4];
#pragma unroll
    for (int nt = 0; nt < 4; ++nt) {
      const uint2 e = pk2[nt][2 * kk], o = pk2[nt][2 * kk + 1];
      unsigned e0 = __shfl((int)e.x, srcA, 64),      e1 = __shfl((int)e.y, srcA, 64);
      unsigned o0 = __shfl((int)o.x, srcA, 64),      o1 = __shfl((int)o.y, srcA, 64);
      unsigned e2 = __shfl((int)e.x, srcA + 16, 64), e3 = __shfl((int)e.y, srcA + 16, 64);
      unsigned o2 = __shfl((int)o.x, srcA + 16, 64), o3 = __shfl((int)o.y, srcA + 16, 64);
      uint4 u;
      u.x = hiSel ? o0 : e0; u.y = hiSel ? o1 : e1;
      u.z = hiSel ? o2 : e2; u.w = hiSel ? o3 : e3;
      pf[nt] = *(bf16x8*)&u;
    }
    __builtin_amdgcn_s_setprio(1);
#pragma unroll
    for (int mt = 0; mt < 2; ++mt)
#pragma unroll
      for (int nt = 0; nt < 4; ++nt)
        oacc[mt][nt] = __builtin_amdgcn_mfma_f32_16x16x32_bf16(vf[kk][mt], pf[nt], oacc[mt][nt], 0, 0, 0);
    __builtin_amdgcn_s_setprio(0);
  }

  // ---- store O head-packed: aout[(win*8+h)*1568 + tok*32 + d] (dense/wave)
  unsigned short* ob = aout + (size_t)(win * 8 + h) * 1568;
#pragma unroll
  for (int nt = 0; nt < 4; ++nt) {
    const int tok = nt * 16 + l15;
    if (tok < 49) {
      unsigned short* op = ob + tok * 32;
      const float rs = rs4[nt];
#pragma unroll
      for (int mt = 0; mt < 2; ++mt) {
        bf16x4 ov;
        ov[0] = (__bf16)(oacc[mt][nt][0] * rs); ov[1] = (__bf16)(oacc[mt][nt][1] * rs);
        ov[2] = (__bf16)(oacc[mt][nt][2] * rs); ov[3] = (__bf16)(oacc[mt][nt][3] * rs);
        *(bf16x4*)(op + mt * 16 + quad * 4) = ov;
      }
    }
  }
}

// ---------------- proj GEMM: A gathered from head-packed aows ---------------
__global__ __launch_bounds__(256) void gemm_proj(
    const unsigned short* __restrict__ A, const unsigned short* __restrict__ W,
    const float* __restrict__ bias, float* __restrict__ Y)
{
  __shared__ __align__(1024) unsigned short sA[128 * 64];
  __shared__ __align__(1024) unsigned short sB[128 * 64];
  const int t = threadIdx.x, w = t >> 6, l = t & 63, quad = l >> 4, l15 = l & 15;
  const int bm = blockIdx.y * 128, bn = blockIdx.x * 128;
  const int wm = (w >> 1) * 64, wn = (w & 1) * 64;
  const int srow = t >> 3, sch = t & 7;
  const int sc = sch ^ (srow & 7);

  // per-lane A gather bases (per i-chunk): row g = bm + i*32 + srow
  size_t abase[4];
#pragma unroll
  for (int i = 0; i < 4; ++i) {
    const int g = bm + i * 32 + srow;
    const unsigned wn_ = (unsigned)(((unsigned long long)g * 87652394ull) >> 32); // g/49
    const int tok = g - (int)wn_ * 49;
    abase[i] = ((size_t)wn_ * 8 + (sc >> 2)) * 1568 + (size_t)tok * 32 + (sc & 3) * 8;
  }

  f32x4 acc[4][4] = {};                      // acc[nW][mA]
  for (int kt = 0; kt < 4; ++kt) {
    const int k0 = kt << 6;
    if (kt) __syncthreads();
#pragma unroll
    for (int i = 0; i < 4; ++i) {
      const int row = i * 32 + srow;
      cp16(A + abase[i] + (size_t)kt * 2 * 1568, sA + (i * 256 + w * 64) * 8);
      cp16(W + (size_t)(bn + row) * 256 + k0 + sc * 8, sB + (i * 256 + w * 64) * 8);
    }
    __syncthreads();
#pragma unroll
    for (int kk = 0; kk < 2; ++kk) {
      bf16x8 xf[4], wf[4];
#pragma unroll
      for (int mt = 0; mt < 4; ++mt)
        xf[mt] = *(const bf16x8*)&sA[(wm + mt * 16 + l15) * 64 + (((4 * kk + quad) ^ (l15 & 7)) * 8)];
#pragma unroll
      for (int nt = 0; nt < 4; ++nt)
        wf[nt] = *(const bf16x8*)&sB[(wn + nt * 16 + l15) * 64 + (((4 * kk + quad) ^ (l15 & 7)) * 8)];
#pragma unroll
      for (int nt = 0; nt < 4; ++nt)
#pragma unroll
        for (int mt = 0; mt < 4; ++mt)
          acc[nt][mt] = __builtin_amdgcn_mfma_f32_16x16x32_bf16(wf[nt], xf[mt], acc[nt][mt], 0, 0, 0);
    }
  }
  // epilogue: lane holds 4 consecutive cols -> f32x4 16B stores
#pragma unroll
  for (int mA = 0; mA < 4; ++mA) {
    const int row = bm + wm + mA * 16 + l15;
    float* orow = Y + (size_t)row * 256;
#pragma unroll
    for (int nW = 0; nW < 4; ++nW) {
      const int c0 = bn + wn + nW * 16 + quad * 4;
      const f32x4 bv = *(const f32x4*)(bias + c0);
      f32x4 v = acc[nW][mA];
      v[0] += bv[0]; v[1] += bv[1]; v[2] += bv[2]; v[3] += bv[3];
      *(f32x4*)(orow + c0) = v;
    }
  }
}

// ---------------------------------------------------------------------------
extern "C" void kernel_launch(void* const* d_in, const int* in_sizes, int n_in,
                              void* d_out, int out_size, void* d_ws, size_t ws_size,
                              hipStream_t stream) {
  const float* x           = (const float*)d_in[0];
  const float* mask        = (const float*)d_in[1];
  const float* qkv_w       = (const float*)d_in[2];
  const float* q_bias      = (const float*)d_in[3];
  const float* v_bias      = (const float*)d_in[4];
  const float* logit_scale = (const float*)d_in[5];
  const float* cpb_w1      = (const float*)d_in[6];
  const float* cpb_b1      = (const float*)d_in[7];
  const float* cpb_w2      = (const float*)d_in[8];
  const float* proj_w      = (const float*)d_in[9];
  const float* proj_b      = (const float*)d_in[10];
  const float* rel_tab     = (const float*)d_in[11];
  const int*   rel_idx     = (const int*)d_in[12];
  float*       out         = (float*)d_out;

  char* ws = (char*)d_ws;
  unsigned short* xbf     = (unsigned short*)(ws + 0);          // 51388416 (bf16 X + pad)
  unsigned short* aows    = (unsigned short*)(ws + 154140672);  // 51380224 (head-packed)
  unsigned short* wq      = (unsigned short*)(ws + 205520896);  // 393216
  unsigned short* wp      = (unsigned short*)(ws + 205914112);  // 131072
  float*          qkvb    = (float*)(ws + 206045184);           // 3072
  float*          table16 = (float*)(ws + 206048256);           // 5632
  float*          bias64  = (float*)(ws + 206053888);           // 131072
  float*          mask64  = (float*)(ws + 206184960);           // 1048576
  // end: 207233536

  prep_kernel<<<1024, 256, 0, stream>>>(qkv_w, proj_w, q_bias, v_bias, wq, wp, qkvb);
  cpb_mlp<<<169, 64, 0, stream>>>(rel_tab, cpb_w1, cpb_b1, cpb_w2, table16);
  bmb<<<1152, 256, 0, stream>>>(table16, rel_idx, mask, bias64, mask64);
  xbf16<<<12546, 256, 0, stream>>>(x, xbf);
  qkv_attn<<<2048, 512, 0, stream>>>(xbf, wq, qkvb, logit_scale, bias64, mask64, aows);
  gemm_proj<<<dim3(2, 784), 256, 0, stream>>>(aows, wp, proj_b, out);
}

// Round 10
// 410.715 us; speedup vs baseline: 2.0540x; 1.0146x over previous
//
#include <hip/hip_runtime.h>

#define DEV __device__ __forceinline__

typedef float  f32x4  __attribute__((ext_vector_type(4)));
typedef __bf16 bf16x4 __attribute__((ext_vector_type(4)));
typedef __bf16 bf16x8 __attribute__((ext_vector_type(8)));

DEV unsigned short f2bf(float f) {
  unsigned u = __float_as_uint(f);
  u += 0x7fffu + ((u >> 16) & 1u);           // round-to-nearest-even
  return (unsigned short)(u >> 16);
}

DEV void cp16(const void* g, void* l) {      // async global->LDS, 16B/lane
  __builtin_amdgcn_global_load_lds((const __attribute__((address_space(1))) void*)g,
                                   (__attribute__((address_space(3))) void*)l, 16, 0, 0);
}

// ---------------- CPB MLP: table16[r][h] = 16*sigmoid(mlp(tab[r])) ----------
__global__ __launch_bounds__(64) void cpb_mlp(
    const float* __restrict__ tab, const float* __restrict__ w1,
    const float* __restrict__ b1, const float* __restrict__ w2,
    float* __restrict__ table16)
{
  int r = blockIdx.x;            // 169 rows
  int t = threadIdx.x;           // 64 lanes
  float x0 = tab[r * 2 + 0], x1 = tab[r * 2 + 1];
  float part[8];
#pragma unroll
  for (int h = 0; h < 8; ++h) part[h] = 0.f;
  for (int j = t; j < 512; j += 64) {
    float hv = fmaxf(w1[j * 2 + 0] * x0 + w1[j * 2 + 1] * x1 + b1[j], 0.f);
#pragma unroll
    for (int h = 0; h < 8; ++h) part[h] += hv * w2[h * 512 + j];
  }
#pragma unroll
  for (int h = 0; h < 8; ++h) {
    float v = part[h];
    for (int off = 32; off > 0; off >>= 1) v += __shfl_down(v, off, 64);
    if (t == 0) table16[r * 8 + h] = 16.f / (1.f + expf(-v));
  }
}

// ======= merged prep: xbf16 + weight-cvt/bias + bias64/mask64 build =========
// blocks [0,12546): X fp32->bf16 (+16 zero pad rows)
// blocks [12546,13570): weights fp32->bf16, qkv bias assembly
// blocks [13570,14722): bias64 (-1e30 pad) & mask64 (0-pad), *log2(e)
__global__ __launch_bounds__(256) void prep_all(
    const float* __restrict__ X, unsigned short* __restrict__ Xb,
    const float* __restrict__ qkv_w, const float* __restrict__ proj_w,
    const float* __restrict__ q_bias, const float* __restrict__ v_bias,
    unsigned short* __restrict__ wq, unsigned short* __restrict__ wp,
    float* __restrict__ qkvb,
    const float* __restrict__ t16, const int* __restrict__ ridx,
    const float* __restrict__ mask, float* __restrict__ bias64,
    float* __restrict__ mask64)
{
  const int b = blockIdx.x;
  if (b < 12546) {                              // ---- X convert
    size_t gid = (size_t)b * 256 + threadIdx.x;
    if (gid < 3211264) {
      const float4* xp = (const float4*)X;
      float4 f0 = xp[2 * gid], f1 = xp[2 * gid + 1];
      bf16x8 u;
      u[0] = (__bf16)f0.x; u[1] = (__bf16)f0.y; u[2] = (__bf16)f0.z; u[3] = (__bf16)f0.w;
      u[4] = (__bf16)f1.x; u[5] = (__bf16)f1.y; u[6] = (__bf16)f1.z; u[7] = (__bf16)f1.w;
      ((bf16x8*)Xb)[gid] = u;
    } else {
      bf16x8 z = {};
      ((bf16x8*)Xb)[gid] = z;                   // zero-pad rows 100352..100367
    }
  } else if (b < 13570) {                       // ---- weights + bias
    int gid = (b - 12546) * 256 + threadIdx.x;  // 262144 = 196608+65536
    if (gid < 196608) wq[gid] = f2bf(qkv_w[gid]);
    else              wp[gid - 196608] = f2bf(proj_w[gid - 196608]);
    if (gid < 768)
      qkvb[gid] = (gid < 256) ? q_bias[gid] : ((gid < 512) ? 0.f : v_bias[gid - 512]);
  } else {                                      // ---- bias64 / mask64
    const float L2E = 1.44269504f;
    int gid = (b - 13570) * 256 + threadIdx.x;  // 294912 = 32768 + 262144
    int p = gid & 4095, i = p >> 6, j = p & 63;
    bool valid = (i < 49) && (j < 49);
    if (gid < 32768) {
      int h = gid >> 12;
      bias64[gid] = valid ? t16[ridx[i * 49 + j] * 8 + h] * L2E : -1e30f;
    } else {
      int g2 = gid - 32768;
      int w = g2 >> 12;
      mask64[g2] = valid ? mask[w * 2401 + i * 49 + j] * L2E : 0.f;
    }
  }
}

// ============ FUSED QKV GEMM + window attention (8 waves, 1 head/wave) ======
// block = 1 window, 512 threads. sX staged once (32 KB cp16). Per-wave LDS =
// 4 KB vT. K/Q fragments lane-local (L2-norm folded pre-bf16). W loads for
// each GEMM are HOISTED into registers up-front (16 outstanding -> one L2
// latency exposure instead of 8 serial ones). launch_bounds(512,2): CUDA
// semantics (2nd arg = blocks/CU) -> 128-VGPR cap (64 spilled ~300MB, r7/r8).
__global__ __launch_bounds__(512, 2) void qkv_attn(
    const unsigned short* __restrict__ Xb, const unsigned short* __restrict__ W,
    const float* __restrict__ qkvb, const float* __restrict__ logit_scale,
    const float* __restrict__ bias64, const float* __restrict__ mask64,
    unsigned short* __restrict__ aout)
{
  __shared__ __align__(1024) char smem[65536];
  const int t = threadIdx.x, w = t >> 6, l = t & 63, quad = l >> 4, l15 = l & 15;
  char* sX = smem;                          // [64 rows][512 B], kt-chunk swizzled
  char* vT = smem + 32768 + w * 4096;       // per-wave V^T scatter region
  const int win = blockIdx.x;               // 2048 windows
  const unsigned short* xrow = Xb + (size_t)(win * 49) * 256;
  const int h = w;                          // wave = head

  // ---- stage X window (rows >= 49 zeroed); wave w -> rows w*8 .. w*8+7 ----
  {
    const int r0 = w * 8;
    const int s = l & 31;                   // 16B slot within 512B row
#pragma unroll
    for (int seg = 0; seg < 4; ++seg) {
      const int row = r0 + 2 * seg + (l >> 5);
      if (row < 49) {
        const unsigned short* src = xrow + (size_t)row * 256
                                  + (s >> 3) * 64 + (((s & 7) ^ (row & 7)) * 8);
        cp16(src, sX + (r0 + 2 * seg) * 512);   // dest: uniform base + lane*16
      } else {
        uint4 z = {};
        *(uint4*)(sX + row * 512 + s * 16) = z;
      }
    }
  }
  __syncthreads();

  // GEMM: M=64 tokens (sX), N=32 head dims, K=256. All 16 W loads hoisted.
  // acc[nt][mA]: lane l15 -> token mA*16+l15 ; quad*4+r -> d = nt*16+quad*4+r.
  auto do_gemm = [&](int wrb, f32x4 (&acc)[2][4]) {
    bf16x8 wreg[2][8];                      // c = kt*2+kk
#pragma unroll
    for (int nt = 0; nt < 2; ++nt) {
      const unsigned short* wr = W + (size_t)(wrb + nt * 16 + l15) * 256;
#pragma unroll
      for (int c = 0; c < 8; ++c)
        wreg[nt][c] = *(const bf16x8*)(wr + (c >> 1) * 64 + (4 * (c & 1) + quad) * 8);
    }
#pragma unroll
    for (int kt = 0; kt < 4; ++kt)
#pragma unroll
      for (int kk = 0; kk < 2; ++kk) {
        bf16x8 xf[4];
#pragma unroll
        for (int mA = 0; mA < 4; ++mA)
          xf[mA] = *(const bf16x8*)(sX + (mA * 16 + l15) * 512 + kt * 128
                                       + (((4 * kk + quad) ^ (l15 & 7)) * 16));
#pragma unroll
        for (int nt = 0; nt < 2; ++nt)
#pragma unroll
          for (int mA = 0; mA < 4; ++mA)
            acc[nt][mA] = __builtin_amdgcn_mfma_f32_16x16x32_bf16(
                wreg[nt][kt * 2 + kk], xf[mA], acc[nt][mA], 0, 0, 0);
      }
  };

  // lane-local acc(+bias) -> L2-NORMALIZED d'-fragment (norm folded pre-bf16)
  auto cvt_norm = [&](f32x4 (&acc)[2][4], const float* bias, float mul,
                      bf16x8 (&f)[4]) {
    const f32x4 b0 = *(const f32x4*)(bias + quad * 4);
    const f32x4 b1 = *(const f32x4*)(bias + 16 + quad * 4);
#pragma unroll
    for (int mt = 0; mt < 4; ++mt) {       // token mt*16+l15
      float v[8];
#pragma unroll
      for (int r = 0; r < 4; ++r) {
        v[r]     = acc[0][mt][r] + b0[r];
        v[4 + r] = acc[1][mt][r] + b1[r];
      }
      float ss = 0.f;
#pragma unroll
      for (int i = 0; i < 8; ++i) ss += v[i] * v[i];
      ss += __shfl_xor(ss, 16, 64); ss += __shfl_xor(ss, 32, 64);
      const float rn = mul / fmaxf(sqrtf(ss), 1e-12f);
#pragma unroll
      for (int i = 0; i < 8; ++i) f[mt][i] = (__bf16)(v[i] * rn);
    }
  };

  // ---- K and Q GEMMs -> normalized in-register fragments ----
  const float scale = __expf(fminf(logit_scale[h], 4.60517019f)) * 1.44269504f;
  bf16x8 kf[4], qf[4];
  {
    f32x4 ka[2][4] = {};
    do_gemm(256 + h * 32, ka);
    cvt_norm(ka, qkvb + 256 + h * 32, 1.f, kf);
  }
  {
    f32x4 qa[2][4] = {};
    do_gemm(h * 32, qa);
    cvt_norm(qa, qkvb + h * 32, scale, qf);   // scale*log2(e) folded into q
  }

  // ---- S^T[j][i] = K . Q^T  (already scaled, log2 domain) ----
  f32x4 sacc[4][4] = {};
  __builtin_amdgcn_s_setprio(1);
#pragma unroll
  for (int mt = 0; mt < 4; ++mt)
#pragma unroll
    for (int nt = 0; nt < 4; ++nt)
      sacc[mt][nt] = __builtin_amdgcn_mfma_f32_16x16x32_bf16(kf[mt], qf[nt], sacc[mt][nt], 0, 0, 0);
  __builtin_amdgcn_s_setprio(0);

  // ---- V GEMM -> vT scatter (true-d rows, swizzled) ----
  {
    f32x4 va[2][4] = {};
    do_gemm(512 + h * 32, va);
    const f32x4 vb0 = *(const f32x4*)(qkvb + 512 + h * 32 + quad * 4);
    const f32x4 vb1 = *(const f32x4*)(qkvb + 512 + h * 32 + 16 + quad * 4);
#pragma unroll
    for (int mA = 0; mA < 4; ++mA) {
      const int tok = mA * 16 + l15;
#pragma unroll
      for (int nt = 0; nt < 2; ++nt) {
#pragma unroll
        for (int r = 0; r < 4; ++r) {
          const int d = nt * 16 + quad * 4 + r;
          *(__bf16*)(vT + d * 128 + (((tok >> 3) ^ (d & 7)) << 4) + (tok & 7) * 2) =
              (__bf16)(va[nt][mA][r] + (nt ? vb1[r] : vb0[r]));
        }
      }
    }
  }

  // ---- softmax (log2 domain) -> pk2 in registers (hides vT scatter) ----
  const float* bh = bias64 + (size_t)h * 4096;
  const float* mw = mask64 + (size_t)(win & 63) * 4096;
  uint2 pk2[4][4];
  float rs4[4];
#pragma unroll
  for (int nt = 0; nt < 4; ++nt) {
    const int i = nt * 16 + l15;
    float mx = -3e38f;
#pragma unroll
    for (int mt = 0; mt < 4; ++mt) {
      const int jb = mt * 16 + quad * 4;
      const f32x4 b4 = *(const f32x4*)(bh + i * 64 + jb);
      const f32x4 m4 = *(const f32x4*)(mw + i * 64 + jb);
#pragma unroll
      for (int r = 0; r < 4; ++r) {
        float sv = sacc[mt][nt][r] + b4[r] + m4[r];
        sacc[mt][nt][r] = sv;
        mx = fmaxf(mx, sv);
      }
    }
    mx = fmaxf(mx, __shfl_xor(mx, 16, 64));
    mx = fmaxf(mx, __shfl_xor(mx, 32, 64));
    float sum = 0.f;
#pragma unroll
    for (int mt = 0; mt < 4; ++mt) {
      float pv[4];
#pragma unroll
      for (int r = 0; r < 4; ++r) {
        pv[r] = __builtin_amdgcn_exp2f(sacc[mt][nt][r] - mx);
        sum += pv[r];
      }
      bf16x4 pk;
      pk[0] = (__bf16)pv[0]; pk[1] = (__bf16)pv[1];
      pk[2] = (__bf16)pv[2]; pk[3] = (__bf16)pv[3];
      pk2[nt][mt] = *(uint2*)&pk;
    }
    sum += __shfl_xor(sum, 16, 64);
    sum += __shfl_xor(sum, 32, 64);
    rs4[nt] = 1.f / sum;                    // normalization deferred to O store
  }

  // ---- vT drain, load vf ----
  asm volatile("s_waitcnt lgkmcnt(0)" ::: "memory");
  __builtin_amdgcn_sched_barrier(0);
  bf16x8 vf[2][2];
#pragma unroll
  for (int kk = 0; kk < 2; ++kk)
#pragma unroll
    for (int mt = 0; mt < 2; ++mt)
      vf[kk][mt] = *(const bf16x8*)(vT + (mt * 16 + l15) * 128
                                       + (((4 * kk + quad) ^ (l15 & 7)) * 16));

  // ---- O^T[d][i] = V^T . P^T ; pf built by cross-quad shuffles ----
  const int srcA = l15 + 32 * (quad & 1);
  const bool hiSel = (quad >> 1) != 0;
  f32x4 oacc[2][4] = {};
#pragma unroll
  for (int kk = 0; kk < 2; ++kk) {
    bf16x8 pf[4];
#pragma unroll
    for (int nt = 0; nt < 4; ++nt) {
      const uint2 e = pk2[nt][2 * kk], o = pk2[nt][2 * kk + 1];
      unsigned e0 = __shfl((int)e.x, srcA, 64),      e1 = __shfl((int)e.y, srcA, 64);
      unsigned o0 = __shfl((int)o.x, srcA, 64),      o1 = __shfl((int)o.y, srcA, 64);
      unsigned e2 = __shfl((int)e.x, srcA + 16, 64), e3 = __shfl((int)e.y, srcA + 16, 64);
      unsigned o2 = __shfl((int)o.x, srcA + 16, 64), o3 = __shfl((int)o.y, srcA + 16, 64);
      uint4 u;
      u.x = hiSel ? o0 : e0; u.y = hiSel ? o1 : e1;
      u.z = hiSel ? o2 : e2; u.w = hiSel ? o3 : e3;
      pf[nt] = *(bf16x8*)&u;
    }
    __builtin_amdgcn_s_setprio(1);
#pragma unroll
    for (int mt = 0; mt < 2; ++mt)
#pragma unroll
      for (int nt = 0; nt < 4; ++nt)
        oacc[mt][nt] = __builtin_amdgcn_mfma_f32_16x16x32_bf16(vf[kk][mt], pf[nt], oacc[mt][nt], 0, 0, 0);
    __builtin_amdgcn_s_setprio(0);
  }

  // ---- store O head-packed: aout[(win*8+h)*1568 + tok*32 + d] (dense/wave)
  unsigned short* ob = aout + (size_t)(win * 8 + h) * 1568;
#pragma unroll
  for (int nt = 0; nt < 4; ++nt) {
    const int tok = nt * 16 + l15;
    if (tok < 49) {
      unsigned short* op = ob + tok * 32;
      const float rs = rs4[nt];
#pragma unroll
      for (int mt = 0; mt < 2; ++mt) {
        bf16x4 ov;
        ov[0] = (__bf16)(oacc[mt][nt][0] * rs); ov[1] = (__bf16)(oacc[mt][nt][1] * rs);
        ov[2] = (__bf16)(oacc[mt][nt][2] * rs); ov[3] = (__bf16)(oacc[mt][nt][3] * rs);
        *(bf16x4*)(op + mt * 16 + quad * 4) = ov;
      }
    }
  }
}

// ---------------- proj GEMM: A gathered from head-packed aows ---------------
__global__ __launch_bounds__(256) void gemm_proj(
    const unsigned short* __restrict__ A, const unsigned short* __restrict__ W,
    const float* __restrict__ bias, float* __restrict__ Y)
{
  __shared__ __align__(1024) unsigned short sA[128 * 64];
  __shared__ __align__(1024) unsigned short sB[128 * 64];
  const int t = threadIdx.x, w = t >> 6, l = t & 63, quad = l >> 4, l15 = l & 15;
  const int bm = blockIdx.y * 128, bn = blockIdx.x * 128;
  const int wm = (w >> 1) * 64, wn = (w & 1) * 64;
  const int srow = t >> 3, sch = t & 7;
  const int sc = sch ^ (srow & 7);

  // per-lane A gather bases (per i-chunk): row g = bm + i*32 + srow
  size_t abase[4];
#pragma unroll
  for (int i = 0; i < 4; ++i) {
    const int g = bm + i * 32 + srow;
    const unsigned wn_ = (unsigned)(((unsigned long long)g * 87652394ull) >> 32); // g/49
    const int tok = g - (int)wn_ * 49;
    abase[i] = ((size_t)wn_ * 8 + (sc >> 2)) * 1568 + (size_t)tok * 32 + (sc & 3) * 8;
  }

  f32x4 acc[4][4] = {};                      // acc[nW][mA]
  for (int kt = 0; kt < 4; ++kt) {
    const int k0 = kt << 6;
    if (kt) __syncthreads();
#pragma unroll
    for (int i = 0; i < 4; ++i) {
      const int row = i * 32 + srow;
      cp16(A + abase[i] + (size_t)kt * 2 * 1568, sA + (i * 256 + w * 64) * 8);
      cp16(W + (size_t)(bn + row) * 256 + k0 + sc * 8, sB + (i * 256 + w * 64) * 8);
    }
    __syncthreads();
#pragma unroll
    for (int kk = 0; kk < 2; ++kk) {
      bf16x8 xf[4], wf[4];
#pragma unroll
      for (int mt = 0; mt < 4; ++mt)
        xf[mt] = *(const bf16x8*)&sA[(wm + mt * 16 + l15) * 64 + (((4 * kk + quad) ^ (l15 & 7)) * 8)];
#pragma unroll
      for (int nt = 0; nt < 4; ++nt)
        wf[nt] = *(const bf16x8*)&sB[(wn + nt * 16 + l15) * 64 + (((4 * kk + quad) ^ (l15 & 7)) * 8)];
#pragma unroll
      for (int nt = 0; nt < 4; ++nt)
#pragma unroll
        for (int mt = 0; mt < 4; ++mt)
          acc[nt][mt] = __builtin_amdgcn_mfma_f32_16x16x32_bf16(wf[nt], xf[mt], acc[nt][mt], 0, 0, 0);
    }
  }
  // epilogue: lane holds 4 consecutive cols -> f32x4 16B stores
#pragma unroll
  for (int mA = 0; mA < 4; ++mA) {
    const int row = bm + wm + mA * 16 + l15;
    float* orow = Y + (size_t)row * 256;
#pragma unroll
    for (int nW = 0; nW < 4; ++nW) {
      const int c0 = bn + wn + nW * 16 + quad * 4;
      const f32x4 bv = *(const f32x4*)(bias + c0);
      f32x4 v = acc[nW][mA];
      v[0] += bv[0]; v[1] += bv[1]; v[2] += bv[2]; v[3] += bv[3];
      *(f32x4*)(orow + c0) = v;
    }
  }
}

// ---------------------------------------------------------------------------
extern "C" void kernel_launch(void* const* d_in, const int* in_sizes, int n_in,
                              void* d_out, int out_size, void* d_ws, size_t ws_size,
                              hipStream_t stream) {
  const float* x           = (const float*)d_in[0];
  const float* mask        = (const float*)d_in[1];
  const float* qkv_w       = (const float*)d_in[2];
  const float* q_bias      = (const float*)d_in[3];
  const float* v_bias      = (const float*)d_in[4];
  const float* logit_scale = (const float*)d_in[5];
  const float* cpb_w1      = (const float*)d_in[6];
  const float* cpb_b1      = (const float*)d_in[7];
  const float* cpb_w2      = (const float*)d_in[8];
  const float* proj_w      = (const float*)d_in[9];
  const float* proj_b      = (const float*)d_in[10];
  const float* rel_tab     = (const float*)d_in[11];
  const int*   rel_idx     = (const int*)d_in[12];
  float*       out         = (float*)d_out;

  char* ws = (char*)d_ws;
  unsigned short* xbf     = (unsigned short*)(ws + 0);          // 51388416 (bf16 X + pad)
  unsigned short* aows    = (unsigned short*)(ws + 154140672);  // 51380224 (head-packed)
  unsigned short* wq      = (unsigned short*)(ws + 205520896);  // 393216
  unsigned short* wp      = (unsigned short*)(ws + 205914112);  // 131072
  float*          qkvb    = (float*)(ws + 206045184);           // 3072
  float*          table16 = (float*)(ws + 206048256);           // 5632
  float*          bias64  = (float*)(ws + 206053888);           // 131072
  float*          mask64  = (float*)(ws + 206184960);           // 1048576
  // end: 207233536

  cpb_mlp<<<169, 64, 0, stream>>>(rel_tab, cpb_w1, cpb_b1, cpb_w2, table16);
  prep_all<<<14722, 256, 0, stream>>>(x, xbf, qkv_w, proj_w, q_bias, v_bias,
                                      wq, wp, qkvb, table16, rel_idx, mask,
                                      bias64, mask64);
  qkv_attn<<<2048, 512, 0, stream>>>(xbf, wq, qkvb, logit_scale, bias64, mask64, aows);
  gemm_proj<<<dim3(2, 784), 256, 0, stream>>>(aows, wp, proj_b, out);
}